// Round 4
// baseline (1306.779 us; speedup 1.0000x reference)
//
#include <hip/hip_runtime.h>
#include <math.h>

typedef unsigned int u32;
typedef unsigned long long u64;

#define A_TOTAL 49152
#define NKEEP 2000
#define NTOPK 300
#define SORTN 4096

// ws layout (bytes)
#define OFF_X      0u            // 512*4096 f32 (pacc during conv1, x after fixup)
#define OFF_POX    8388608u      // 60*4*4096 f64 partials      (7864320)
#define OFF_BOXES  16252928u     // 49152*4 f32                 (786432)
#define OFF_SCORES 17039360u     // 49152 f32                   (196608)
#define OFF_HIST   17235968u     // 65536 u32                   (262144)
#define OFF_KEYS   17498112u     // 4096 u64                    (32768)
#define OFF_CAND5  17530880u     // 2048*5 f32                  (40960)
#define OFF_MASK   17571840u     // 2048*32 u64                 (524288)
#define OFF_MISC   18096128u     // [0]=counter,[1]=B1 ; +64B: suppws u64[32]

__global__ __launch_bounds__(256) void k_init(u32* __restrict__ hist, u64* __restrict__ keys,
                                              u32* __restrict__ misc, float* __restrict__ out) {
    int t = blockIdx.x * 256 + threadIdx.x;
    if (t < 65536) hist[t] = 0u;
    if (t < SORTN) keys[t] = 0ull;
    if (t < NTOPK * 5) out[t] = 0.f;
    if (t == 0) misc[0] = 0u;
}

__global__ __launch_bounds__(256) void k_zero(float* __restrict__ p) {
    p[blockIdx.x * 256 + threadIdx.x] = 0.f;   // grid 8192 = 2M floats
}

// conv1: 3x3, 1024->512, pad 1. R2-validated structure (64co x 8x8 px tile, 16 outputs/thread,
// 8-ci chunks, f32 chunk accum + f64 across chunks) + K-split x2 (z = ci-half) for occupancy:
// 1024 blocks = 4/CU = 4 waves/SIMD. Each block atomicAdds its f32-rounded partial into
// pre-zeroed pacc (exactly 2 commutative contributions per cell -> deterministic).
__global__ __launch_bounds__(256, 4) void k_conv1(const float* __restrict__ fx, const float* __restrict__ w1,
                                                  float* __restrict__ pacc) {
    __shared__ float sfx[8 * 120];     // [ci][iy(10)][ix(12)]
    __shared__ float swT[72 * 66];     // [ci*9+tap][co padded to 66]
    const int tid = threadIdx.x;
    const int co0 = blockIdx.x * 64;
    const int tile = blockIdx.y;
    const int ty0 = (tile >> 3) << 3;
    const int tx0 = (tile & 7) << 3;
    const int tx = tid & 31;   // co pair
    const int ty = tid >> 5;   // pixel row 0..7
    const int base = blockIdx.z * 64;  // chunk range [base, base+64)

    // --- staging descriptors (chunk-invariant) ---
    int fx_g[4], fx_l[4];
    bool fx_wr[4], fx_ld[4];
#pragma unroll
    for (int j = 0; j < 4; j++) {
        int e = tid + j * 256;
        int ci = e / 120, r = e - ci * 120;
        int iy = r / 12, ix = r - iy * 12;
        int gy = ty0 + iy - 1, gx = tx0 + ix - 1;
        bool wr = (e < 960) && (ix < 10);
        bool ld = wr && (gy >= 0) && (gy < 64) && (gx >= 0) && (gx < 64);
        fx_wr[j] = wr;
        fx_ld[j] = ld;
        fx_g[j] = ci * 4096 + gy * 64 + gx;
        fx_l[j] = wr ? (ci * 120 + iy * 12 + ix) : 0;
    }
    int w_g[18], w_l[18];
#pragma unroll
    for (int j = 0; j < 18; j++) {
        int e = tid + j * 256;             // 18*256 = 4608 = 64co * 8ci * 9tap
        int co = e / 72, r = e - co * 72;
        int ci = r / 9, tap = r - ci * 9;
        w_g[j] = co * 9216 + ci * 9 + tap; // coalesced: r contiguous in w1 per co
        w_l[j] = (ci * 9 + tap) * 66 + co;
    }

    double accD[2][8];
#pragma unroll
    for (int c = 0; c < 2; c++)
#pragma unroll
        for (int p = 0; p < 8; p++) accD[c][p] = 0.0;

    float pw[18], pfx[4];
    // prefetch first chunk of this half
    {
        const float* wbase = w1 + (size_t)co0 * 9216 + (size_t)base * 72;
        const float* fbase = fx + (size_t)base * 8 * 4096;
#pragma unroll
        for (int j = 0; j < 18; j++) pw[j] = wbase[w_g[j]];
#pragma unroll
        for (int j = 0; j < 4; j++) pfx[j] = fx_ld[j] ? fbase[fx_g[j]] : 0.f;
    }

#pragma unroll 1
    for (int cc = base; cc < base + 64; cc++) {
        __syncthreads();                   // previous compute done; LDS writable
#pragma unroll
        for (int j = 0; j < 18; j++) swT[w_l[j]] = pw[j];
#pragma unroll
        for (int j = 0; j < 4; j++)
            if (fx_wr[j]) sfx[fx_l[j]] = pfx[j];
        if (cc < base + 63) {              // issue next chunk's loads; land during compute
            int ci0 = (cc + 1) * 8;
            const float* wbase = w1 + (size_t)co0 * 9216 + (size_t)ci0 * 9;
            const float* fbase = fx + (size_t)ci0 * 4096;
#pragma unroll
            for (int j = 0; j < 18; j++) pw[j] = wbase[w_g[j]];
#pragma unroll
            for (int j = 0; j < 4; j++) pfx[j] = fx_ld[j] ? fbase[fx_g[j]] : 0.f;
        }
        __syncthreads();

        float acc[2][8];
#pragma unroll
        for (int c = 0; c < 2; c++)
#pragma unroll
            for (int p = 0; p < 8; p++) acc[c][p] = 0.f;

#pragma unroll 1
        for (int ci = 0; ci < 8; ci++) {
#pragma unroll
            for (int dy = 0; dy < 3; dy++) {
                const float* row = &sfx[ci * 120 + (ty + dy) * 12];
                float4 ra = *(const float4*)row;
                float4 rb = *(const float4*)(row + 4);
                float2 rc = *(const float2*)(row + 8);
                float r[10] = {ra.x, ra.y, ra.z, ra.w, rb.x, rb.y, rb.z, rb.w, rc.x, rc.y};
#pragma unroll
                for (int dx = 0; dx < 3; dx++) {
                    float2 wv = *(const float2*)&swT[(ci * 9 + dy * 3 + dx) * 66 + tx * 2];
#pragma unroll
                    for (int p = 0; p < 8; p++) {
                        acc[0][p] += r[p + dx] * wv.x;
                        acc[1][p] += r[p + dx] * wv.y;
                    }
                }
            }
        }
#pragma unroll
        for (int c = 0; c < 2; c++)
#pragma unroll
            for (int p = 0; p < 8; p++) accD[c][p] += (double)acc[c][p];
    }

#pragma unroll
    for (int c = 0; c < 2; c++) {
        int co = co0 + tx * 2 + c;
#pragma unroll
        for (int p = 0; p < 8; p++)
            atomicAdd(&pacc[(size_t)co * 4096 + (ty0 + ty) * 64 + tx0 + p], (float)accD[c][p]);
    }
}

// x = relu(pacc + bias), in place
__global__ __launch_bounds__(256) void k_fixup(float* __restrict__ x, const float* __restrict__ b1) {
    int i = blockIdx.x * 256 + threadIdx.x;    // grid 8192
    x[i] = fmaxf(x[i] + b1[i >> 12], 0.f);
}

// 1x1 convs, LDS-tiled, ci-quarter partials (f64), bias added later in k_boxes.
// grid (64 px-tiles, 4 ci-quarters), block 256 = 64 px x 4 o-groups (15 o each).
__global__ __launch_bounds__(256) void k_conv23(const float* __restrict__ x,
                                                const float* __restrict__ w2, const float* __restrict__ w3,
                                                double* __restrict__ pox) {
    __shared__ float xs[32 * 64];     // [ci][px]
    __shared__ float wsh[60 * 128];   // [o][ci]
    const int tid = threadIdx.x;
    const int px0 = blockIdx.x * 64;
    const int cib = blockIdx.y * 128;
    const int px = tid & 63;
    const int og = tid >> 6;          // 0..3 -> o = og*15 + j

#pragma unroll
    for (int k = 0; k < 30; k++) {
        int e = tid + k * 256;
        int o = e >> 7, ci = e & 127;
        float wv = (o < 12) ? w2[o * 512 + cib + ci] : w3[(size_t)(o - 12) * 512 + cib + ci];
        wsh[o * 128 + ci] = wv;
    }

    double acc[15];
#pragma unroll
    for (int j = 0; j < 15; j++) acc[j] = 0.0;

#pragma unroll 1
    for (int ch = 0; ch < 4; ch++) {
        __syncthreads();
#pragma unroll
        for (int k = 0; k < 8; k++) {
            int e = tid + k * 256;
            int ci = e >> 6, p = e & 63;
            xs[ci * 64 + p] = x[(size_t)(cib + ch * 32 + ci) * 4096 + px0 + p];
        }
        __syncthreads();
#pragma unroll 1
        for (int ci = 0; ci < 32; ci++) {
            double xd = (double)xs[ci * 64 + px];
            const float* wrow = &wsh[ch * 32 + ci];
#pragma unroll
            for (int j = 0; j < 15; j++)
                acc[j] = fma(xd, (double)wrow[(og * 15 + j) * 128], acc[j]);
        }
    }
#pragma unroll
    for (int j = 0; j < 15; j++) {
        int o = og * 15 + j;
        pox[((size_t)o * 4 + blockIdx.y) * 4096 + px0 + px] = acc[j];
    }
}

// decode: combine ci-quarter partials (+bias, round f32), f64 sigmoid/box decode, histogram
__global__ __launch_bounds__(256) void k_boxes(const double* __restrict__ pox,
                                               const float* __restrict__ b2, const float* __restrict__ b3,
                                               const int* __restrict__ imh, const int* __restrict__ imw,
                                               float* __restrict__ boxes, float* __restrict__ scores,
                                               u32* __restrict__ hist) {
    int idx = blockIdx.x * 256 + threadIdx.x;
    if (idx >= A_TOTAL) return;
    int px = idx / 12, a = idx - px * 12;

    double t = 0.0;
#pragma unroll
    for (int q = 0; q < 4; q++) t += pox[((size_t)a * 4 + q) * 4096 + px];
    float o = (float)(t + (double)b2[a]);
    float s = (float)(1.0 / (1.0 + exp(-(double)o)));
    scores[idx] = s;
    atomicAdd(&hist[__float_as_uint(s) >> 16], 1u);

    float d[4];
#pragma unroll
    for (int c = 0; c < 4; c++) {
        int oo = 12 + a * 4 + c;
        double u = 0.0;
#pragma unroll
        for (int q = 0; q < 4; q++) u += pox[((size_t)oo * 4 + q) * 4096 + px];
        d[c] = (float)(u + (double)b3[a * 4 + c]);
    }

    int py = px >> 6, pxx = px & 63;
    double cx = pxx * 16.0 + 8.0, cy = py * 16.0 + 8.0;
    int si = a / 3, ri = a - si * 3;
    double scale = (double)(32 << si);
    double ratio = 0.5 * (double)(1 << ri);
    double sq = sqrt(ratio);
    double aw = scale * sq, ah = scale / sq;
    double xc = cx + (double)d[0] * aw;
    double yc = cy + (double)d[1] * ah;
    double wv = aw * exp((double)d[2]);
    double hv = ah * exp((double)d[3]);
    float W = (float)imw[0], H = (float)imh[0];
    float x1 = fminf(fmaxf((float)(xc - wv * 0.5), 0.f), W);
    float x2 = fminf(fmaxf((float)(xc + wv * 0.5), 0.f), W);
    float y1 = fminf(fmaxf((float)(yc - hv * 0.5), 0.f), H);
    float y2 = fminf(fmaxf((float)(yc + hv * 0.5), 0.f), H);
    boxes[(size_t)idx * 4 + 0] = x1;
    boxes[(size_t)idx * 4 + 1] = y1;
    boxes[(size_t)idx * 4 + 2] = x2;
    boxes[(size_t)idx * 4 + 3] = y2;
}

// find boundary bin B1 so that count(bins >= B1) >= 2000, count(bins > B1) < 2000
__global__ __launch_bounds__(256) void k_scanhist(const u32* __restrict__ hist, u32* __restrict__ misc) {
    __shared__ u32 csum[256];
    __shared__ u32 cb[256];
    __shared__ int s_cidx;
    __shared__ u32 s_cacc;
    int t = threadIdx.x;
    u32 sum = 0;
    const uint4* h4 = (const uint4*)(hist + t * 256);
    for (int j = 0; j < 64; j++) { uint4 v = h4[j]; sum += v.x + v.y + v.z + v.w; }
    csum[t] = sum;
    __syncthreads();
    if (t == 0) {
        u32 acc = 0;
        int c = 255;
        for (; c > 0; c--) {
            if (acc + csum[c] >= NKEEP) break;
            acc += csum[c];
        }
        s_cidx = c;
        s_cacc = acc;
    }
    __syncthreads();
    cb[t] = hist[s_cidx * 256 + t];
    __syncthreads();
    if (t == 0) {
        u32 acc = s_cacc;
        int b = 255;
        for (; b > 0; b--) {
            acc += cb[b];
            if (acc >= NKEEP) break;
        }
        misc[1] = (u32)(s_cidx * 256 + b);
    }
}

__global__ __launch_bounds__(256) void k_compact(const float* __restrict__ scores, u32* __restrict__ misc,
                                                 u64* __restrict__ keys) {
    int idx = blockIdx.x * 256 + threadIdx.x;
    if (idx >= A_TOTAL) return;
    u32 bits = __float_as_uint(scores[idx]);
    if ((bits >> 16) >= misc[1]) {
        u32 slot = atomicAdd(&misc[0], 1u);
        if (slot < SORTN) keys[slot] = ((u64)bits << 32) | (u64)(~(u32)idx);
    }
}

// bitonic sort 4096 keys DESC (score desc, index asc), then gather cand rows + init suppression words
__global__ __launch_bounds__(1024) void k_sort(const u64* __restrict__ keys, const float* __restrict__ boxes,
                                               float* __restrict__ cand5, u64* __restrict__ suppws) {
    __shared__ u64 lk[SORTN];
    int t = threadIdx.x;
#pragma unroll
    for (int r = 0; r < 4; r++) lk[r * 1024 + t] = keys[r * 1024 + t];
    for (int kk = 2; kk <= SORTN; kk <<= 1) {
        for (int jj = kk >> 1; jj > 0; jj >>= 1) {
            __syncthreads();
#pragma unroll
            for (int rep = 0; rep < 4; rep++) {
                int i = rep * 1024 + t;
                int ixj = i ^ jj;
                if (ixj > i) {
                    u64 a = lk[i], b = lk[ixj];
                    bool sw = ((i & kk) == 0) ? (a < b) : (a > b);  // descending overall
                    if (sw) { lk[i] = b; lk[ixj] = a; }
                }
            }
        }
    }
    __syncthreads();
#pragma unroll
    for (int rep = 0; rep < 2; rep++) {
        int i = rep * 1024 + t;
        bool suppb = true;
        float c0 = 0.f, c1 = 0.f, c2 = 0.f, c3 = 0.f, cs = 0.f;
        if (i < NKEEP) {
            u64 key = lk[i];
            u32 idx = ~(u32)(key & 0xFFFFFFFFull);
            cs = __uint_as_float((u32)(key >> 32));
            c0 = boxes[(size_t)idx * 4 + 0];
            c1 = boxes[(size_t)idx * 4 + 1];
            c2 = boxes[(size_t)idx * 4 + 2];
            c3 = boxes[(size_t)idx * 4 + 3];
            bool valid = ((c2 - c0) >= 16.f) && ((c3 - c1) >= 16.f) && (cs >= 0.05f);
            suppb = !valid;
        }
        cand5[i * 5 + 0] = c0;
        cand5[i * 5 + 1] = c1;
        cand5[i * 5 + 2] = c2;
        cand5[i * 5 + 3] = c3;
        cand5[i * 5 + 4] = cs;
        u64 bal = __ballot(suppb ? 1 : 0);
        if ((t & 63) == 0) suppws[i >> 6] = bal;
    }
}

// IoU > 0.7 bitmask, 64x64 tiles
__global__ __launch_bounds__(64) void k_mask(const float* __restrict__ cand5, u64* __restrict__ mask) {
    __shared__ float cb[64][5];
    int t = threadIdx.x;
    int bi = blockIdx.y, bj = blockIdx.x;
    int j = bj * 64 + t;
    {
        float b0 = cand5[j * 5 + 0], b1v = cand5[j * 5 + 1], b2v = cand5[j * 5 + 2], b3v = cand5[j * 5 + 3];
        cb[t][0] = b0; cb[t][1] = b1v; cb[t][2] = b2v; cb[t][3] = b3v;
        cb[t][4] = (b2v - b0) * (b3v - b1v);
    }
    __syncthreads();
    int i = bi * 64 + t;
    float r0 = cand5[i * 5 + 0], r1 = cand5[i * 5 + 1], r2 = cand5[i * 5 + 2], r3 = cand5[i * 5 + 3];
    float ra = (r2 - r0) * (r3 - r1);
    u64 bits = 0ull;
#pragma unroll 4
    for (int c = 0; c < 64; c++) {
        float lx = fmaxf(r0, cb[c][0]);
        float ly = fmaxf(r1, cb[c][1]);
        float rx = fminf(r2, cb[c][2]);
        float ry = fminf(r3, cb[c][3]);
        float w = fmaxf(rx - lx, 0.f);
        float h = fmaxf(ry - ly, 0.f);
        float inter = w * h;
        float iou = inter / fmaxf(ra + cb[c][4] - inter, 1e-6f);
        if (iou > 0.7f) bits |= (1ull << c);
    }
    mask[(size_t)i * 32 + bj] = bits;
}

// single-wave greedy NMS scan with depth-8 prefetch; writes first <=300 kept rows
__global__ __launch_bounds__(64) void k_scan(const u64* __restrict__ mask, const float* __restrict__ cand5,
                                             const u64* __restrict__ suppws, float* __restrict__ out) {
    int lane = threadIdx.x;
    u64 supp = (lane < 32) ? suppws[lane] : 0ull;
    u64 bufA[8], bufB[8];
    float dA[8], dB[8];
#pragma unroll
    for (int k = 0; k < 8; k++) {
        bufA[k] = (lane < 32) ? mask[(size_t)k * 32 + lane] : 0ull;
        dA[k] = (lane < 5) ? cand5[k * 5 + lane] : 0.f;
    }
    int kcount = 0;
    for (int g = 0; g < 256; g++) {
        int base = g * 8;
        if (g < 255) {
            int nb = base + 8;
#pragma unroll
            for (int k = 0; k < 8; k++) {
                bufB[k] = (lane < 32) ? mask[(size_t)(nb + k) * 32 + lane] : 0ull;
                dB[k] = (lane < 5) ? cand5[(nb + k) * 5 + lane] : 0.f;
            }
        }
        int w = g >> 3;
        u64 cur = __shfl(supp, w);
#pragma unroll
        for (int k = 0; k < 8; k++) {
            int i = base + k;
            if (i < NKEEP && !((cur >> (i & 63)) & 1ull)) {
                if (kcount < NTOPK) {
                    if (lane < 5) out[kcount * 5 + lane] = dA[k];
                    kcount++;
                }
                supp |= bufA[k];
                cur |= __shfl(bufA[k], w);
            }
        }
        if (kcount >= NTOPK) return;
#pragma unroll
        for (int k = 0; k < 8; k++) { bufA[k] = bufB[k]; dA[k] = dB[k]; }
    }
}

extern "C" void kernel_launch(void* const* d_in, const int* in_sizes, int n_in,
                              void* d_out, int out_size, void* d_ws, size_t ws_size,
                              hipStream_t stream) {
    (void)in_sizes; (void)n_in; (void)out_size; (void)ws_size;
    const float* fx = (const float*)d_in[0];
    const float* w1 = (const float*)d_in[1];
    const float* b1 = (const float*)d_in[2];
    const float* w2 = (const float*)d_in[3];
    const float* b2 = (const float*)d_in[4];
    const float* w3 = (const float*)d_in[5];
    const float* b3 = (const float*)d_in[6];
    const int* imh = (const int*)d_in[7];
    const int* imw = (const int*)d_in[8];

    char* ws = (char*)d_ws;
    float*  x      = (float*)(ws + OFF_X);     // pacc during conv1, x after fixup
    double* pox    = (double*)(ws + OFF_POX);
    float*  boxes  = (float*)(ws + OFF_BOXES);
    float*  scores = (float*)(ws + OFF_SCORES);
    u32*    hist   = (u32*)(ws + OFF_HIST);
    u64*    keys   = (u64*)(ws + OFF_KEYS);
    float*  cand5  = (float*)(ws + OFF_CAND5);
    u64*    mask   = (u64*)(ws + OFF_MASK);
    u32*    misc   = (u32*)(ws + OFF_MISC);
    u64*    suppws = (u64*)(ws + OFF_MISC + 64);
    float*  out    = (float*)d_out;

    k_init<<<256, 256, 0, stream>>>(hist, keys, misc, out);
    k_zero<<<8192, 256, 0, stream>>>(x);
    k_conv1<<<dim3(8, 64, 2), 256, 0, stream>>>(fx, w1, x);
    k_fixup<<<8192, 256, 0, stream>>>(x, b1);
    k_conv23<<<dim3(64, 4), 256, 0, stream>>>(x, w2, w3, pox);
    k_boxes<<<192, 256, 0, stream>>>(pox, b2, b3, imh, imw, boxes, scores, hist);
    k_scanhist<<<1, 256, 0, stream>>>(hist, misc);
    k_compact<<<192, 256, 0, stream>>>(scores, misc, keys);
    k_sort<<<1, 1024, 0, stream>>>(keys, boxes, cand5, suppws);
    k_mask<<<dim3(32, 32), 64, 0, stream>>>(cand5, mask);
    k_scan<<<1, 64, 0, stream>>>(mask, cand5, suppws, out);
}

// Round 5
// 794.478 us; speedup vs baseline: 1.6448x; 1.6448x over previous
//
#include <hip/hip_runtime.h>
#include <math.h>

typedef unsigned int u32;
typedef unsigned long long u64;

#define A_TOTAL 49152
#define NKEEP 2000
#define NTOPK 300
#define SORTN 4096

// ws layout (bytes)
#define OFF_X      0u            // 512*4096 f32                (8388608)
#define OFF_POX    8388608u      // 60*4*4096 f64 partials      (7864320)
#define OFF_BOXES  16252928u     // 49152*4 f32                 (786432)
#define OFF_SCORES 17039360u     // 49152 f32                   (196608)
#define OFF_HIST   17235968u     // 65536 u32                   (262144)
#define OFF_KEYS   17498112u     // 4096 u64                    (32768)
#define OFF_CAND5  17530880u     // 2048*5 f32                  (40960)
#define OFF_MASK   17571840u     // 2048*32 u64                 (524288)
#define OFF_MISC   18096128u     // [0]=counter,[1]=B1 ; +64B: suppws u64[32]

__global__ __launch_bounds__(256) void k_init(u32* __restrict__ hist, u64* __restrict__ keys,
                                              u32* __restrict__ misc, float* __restrict__ out) {
    int t = blockIdx.x * 256 + threadIdx.x;
    if (t < 65536) hist[t] = 0u;
    if (t < SORTN) keys[t] = 0ull;
    if (t < NTOPK * 5) out[t] = 0.f;
    if (t == 0) misc[0] = 0u;
}

// conv1: 3x3, 1024->512, pad 1, ReLU. R2-validated tile (64co x 8x8 px, 16 outputs/thread,
// 8-ci chunks, f32 chunk accum + f64 across chunks -> bitwise-identical outputs to R2).
// New: double-buffered LDS (ONE barrier per chunk) + full ci-unroll for deep lgkm pipelining.
// Occupancy is grid-limited (512 blocks = 2/CU = 2 waves/SIMD) so VGPR up to 256 is free.
__global__ __launch_bounds__(256) void k_conv1(const float* __restrict__ fx, const float* __restrict__ w1,
                                               const float* __restrict__ b1, float* __restrict__ xout) {
    __shared__ float sfx[2][8 * 120];   // [buf][ci][iy(10)][ix(12)]
    __shared__ float swT[2][72 * 66];   // [buf][ci*9+tap][co padded to 66]
    const int tid = threadIdx.x;
    const int co0 = blockIdx.x * 64;
    const int tile = blockIdx.y;
    const int ty0 = (tile >> 3) << 3;
    const int tx0 = (tile & 7) << 3;
    const int tx = tid & 31;   // co pair
    const int ty = tid >> 5;   // pixel row 0..7

    // --- staging descriptors (chunk-invariant) ---
    int fx_g[4], fx_l[4];
    bool fx_wr[4], fx_ld[4];
#pragma unroll
    for (int j = 0; j < 4; j++) {
        int e = tid + j * 256;
        int ci = e / 120, r = e - ci * 120;
        int iy = r / 12, ix = r - iy * 12;
        int gy = ty0 + iy - 1, gx = tx0 + ix - 1;
        bool wr = (e < 960) && (ix < 10);
        bool ld = wr && (gy >= 0) && (gy < 64) && (gx >= 0) && (gx < 64);
        fx_wr[j] = wr;
        fx_ld[j] = ld;
        fx_g[j] = ci * 4096 + gy * 64 + gx;
        fx_l[j] = wr ? (ci * 120 + iy * 12 + ix) : 0;
    }
    int w_g[18], w_l[18];
#pragma unroll
    for (int j = 0; j < 18; j++) {
        int e = tid + j * 256;             // 18*256 = 4608 = 64co * 8ci * 9tap
        int co = e / 72, r = e - co * 72;
        int ci = r / 9, tap = r - ci * 9;
        w_g[j] = co * 9216 + ci * 9 + tap; // coalesced: r contiguous in w1 per co
        w_l[j] = (ci * 9 + tap) * 66 + co;
    }

    double accD[2][8];
#pragma unroll
    for (int c = 0; c < 2; c++)
#pragma unroll
        for (int p = 0; p < 8; p++) accD[c][p] = 0.0;

    float pw[18], pfx[4];
    // prefetch chunk 0, write buf0, prefetch chunk 1
    {
        const float* wbase = w1 + (size_t)co0 * 9216;
#pragma unroll
        for (int j = 0; j < 18; j++) pw[j] = wbase[w_g[j]];
#pragma unroll
        for (int j = 0; j < 4; j++) pfx[j] = fx_ld[j] ? fx[fx_g[j]] : 0.f;
#pragma unroll
        for (int j = 0; j < 18; j++) swT[0][w_l[j]] = pw[j];
#pragma unroll
        for (int j = 0; j < 4; j++)
            if (fx_wr[j]) sfx[0][fx_l[j]] = pfx[j];
        const float* wb1 = wbase + 72;
        const float* fb1 = fx + 8 * 4096;
#pragma unroll
        for (int j = 0; j < 18; j++) pw[j] = wb1[w_g[j]];
#pragma unroll
        for (int j = 0; j < 4; j++) pfx[j] = fx_ld[j] ? fb1[fx_g[j]] : 0.f;
    }

#pragma unroll 1
    for (int cc = 0; cc < 128; cc++) {
        const int b = cc & 1;
        __syncthreads();   // buf b writes visible; all waves done reading buf b^1
        if (cc < 127) {    // stage prefetched chunk cc+1 into the other buffer
#pragma unroll
            for (int j = 0; j < 18; j++) swT[b ^ 1][w_l[j]] = pw[j];
#pragma unroll
            for (int j = 0; j < 4; j++)
                if (fx_wr[j]) sfx[b ^ 1][fx_l[j]] = pfx[j];
        }
        if (cc < 126) {    // issue loads for chunk cc+2; land during compute
            int ci0 = (cc + 2) * 8;
            const float* wbase = w1 + (size_t)co0 * 9216 + (size_t)ci0 * 9;
            const float* fbase = fx + (size_t)ci0 * 4096;
#pragma unroll
            for (int j = 0; j < 18; j++) pw[j] = wbase[w_g[j]];
#pragma unroll
            for (int j = 0; j < 4; j++) pfx[j] = fx_ld[j] ? fbase[fx_g[j]] : 0.f;
        }

        float acc[2][8];
#pragma unroll
        for (int c = 0; c < 2; c++)
#pragma unroll
            for (int p = 0; p < 8; p++) acc[c][p] = 0.f;

#pragma unroll
        for (int ci = 0; ci < 8; ci++) {
#pragma unroll
            for (int dy = 0; dy < 3; dy++) {
                const float* row = &sfx[b][ci * 120 + (ty + dy) * 12];
                float4 ra = *(const float4*)row;
                float4 rb = *(const float4*)(row + 4);
                float2 rc = *(const float2*)(row + 8);
                float r[10] = {ra.x, ra.y, ra.z, ra.w, rb.x, rb.y, rb.z, rb.w, rc.x, rc.y};
#pragma unroll
                for (int dx = 0; dx < 3; dx++) {
                    float2 wv = *(const float2*)&swT[b][(ci * 9 + dy * 3 + dx) * 66 + tx * 2];
#pragma unroll
                    for (int p = 0; p < 8; p++) {
                        acc[0][p] += r[p + dx] * wv.x;
                        acc[1][p] += r[p + dx] * wv.y;
                    }
                }
            }
        }
#pragma unroll
        for (int c = 0; c < 2; c++)
#pragma unroll
            for (int p = 0; p < 8; p++) accD[c][p] += (double)acc[c][p];
    }

#pragma unroll
    for (int c = 0; c < 2; c++) {
        int co = co0 + tx * 2 + c;
        double bb = (double)b1[co];
#pragma unroll
        for (int p = 0; p < 8; p++) {
            float v = (float)(accD[c][p] + bb);
            xout[(size_t)co * 4096 + (ty0 + ty) * 64 + tx0 + p] = fmaxf(v, 0.f);
        }
    }
}

// 1x1 convs, LDS-tiled, ci-quarter partials (f64), bias added later in k_boxes.
// grid (64 px-tiles, 4 ci-quarters), block 256 = 64 px x 4 o-groups (15 o each).
__global__ __launch_bounds__(256) void k_conv23(const float* __restrict__ x,
                                                const float* __restrict__ w2, const float* __restrict__ w3,
                                                double* __restrict__ pox) {
    __shared__ float xs[32 * 64];     // [ci][px]
    __shared__ float wsh[60 * 128];   // [o][ci]
    const int tid = threadIdx.x;
    const int px0 = blockIdx.x * 64;
    const int cib = blockIdx.y * 128;
    const int px = tid & 63;
    const int og = tid >> 6;          // 0..3 -> o = og*15 + j

#pragma unroll
    for (int k = 0; k < 30; k++) {
        int e = tid + k * 256;
        int o = e >> 7, ci = e & 127;
        float wv = (o < 12) ? w2[o * 512 + cib + ci] : w3[(size_t)(o - 12) * 512 + cib + ci];
        wsh[o * 128 + ci] = wv;
    }

    double acc[15];
#pragma unroll
    for (int j = 0; j < 15; j++) acc[j] = 0.0;

#pragma unroll 1
    for (int ch = 0; ch < 4; ch++) {
        __syncthreads();
#pragma unroll
        for (int k = 0; k < 8; k++) {
            int e = tid + k * 256;
            int ci = e >> 6, p = e & 63;
            xs[ci * 64 + p] = x[(size_t)(cib + ch * 32 + ci) * 4096 + px0 + p];
        }
        __syncthreads();
#pragma unroll 1
        for (int ci = 0; ci < 32; ci++) {
            double xd = (double)xs[ci * 64 + px];
            const float* wrow = &wsh[ch * 32 + ci];
#pragma unroll
            for (int j = 0; j < 15; j++)
                acc[j] = fma(xd, (double)wrow[(og * 15 + j) * 128], acc[j]);
        }
    }
#pragma unroll
    for (int j = 0; j < 15; j++) {
        int o = og * 15 + j;
        pox[((size_t)o * 4 + blockIdx.y) * 4096 + px0 + px] = acc[j];
    }
}

// decode: combine ci-quarter partials (+bias, round f32), f64 sigmoid/box decode, histogram
__global__ __launch_bounds__(256) void k_boxes(const double* __restrict__ pox,
                                               const float* __restrict__ b2, const float* __restrict__ b3,
                                               const int* __restrict__ imh, const int* __restrict__ imw,
                                               float* __restrict__ boxes, float* __restrict__ scores,
                                               u32* __restrict__ hist) {
    int idx = blockIdx.x * 256 + threadIdx.x;
    if (idx >= A_TOTAL) return;
    int px = idx / 12, a = idx - px * 12;

    double t = 0.0;
#pragma unroll
    for (int q = 0; q < 4; q++) t += pox[((size_t)a * 4 + q) * 4096 + px];
    float o = (float)(t + (double)b2[a]);
    float s = (float)(1.0 / (1.0 + exp(-(double)o)));
    scores[idx] = s;
    atomicAdd(&hist[__float_as_uint(s) >> 16], 1u);

    float d[4];
#pragma unroll
    for (int c = 0; c < 4; c++) {
        int oo = 12 + a * 4 + c;
        double u = 0.0;
#pragma unroll
        for (int q = 0; q < 4; q++) u += pox[((size_t)oo * 4 + q) * 4096 + px];
        d[c] = (float)(u + (double)b3[a * 4 + c]);
    }

    int py = px >> 6, pxx = px & 63;
    double cx = pxx * 16.0 + 8.0, cy = py * 16.0 + 8.0;
    int si = a / 3, ri = a - si * 3;
    double scale = (double)(32 << si);
    double ratio = 0.5 * (double)(1 << ri);
    double sq = sqrt(ratio);
    double aw = scale * sq, ah = scale / sq;
    double xc = cx + (double)d[0] * aw;
    double yc = cy + (double)d[1] * ah;
    double wv = aw * exp((double)d[2]);
    double hv = ah * exp((double)d[3]);
    float W = (float)imw[0], H = (float)imh[0];
    float x1 = fminf(fmaxf((float)(xc - wv * 0.5), 0.f), W);
    float x2 = fminf(fmaxf((float)(xc + wv * 0.5), 0.f), W);
    float y1 = fminf(fmaxf((float)(yc - hv * 0.5), 0.f), H);
    float y2 = fminf(fmaxf((float)(yc + hv * 0.5), 0.f), H);
    boxes[(size_t)idx * 4 + 0] = x1;
    boxes[(size_t)idx * 4 + 1] = y1;
    boxes[(size_t)idx * 4 + 2] = x2;
    boxes[(size_t)idx * 4 + 3] = y2;
}

// find boundary bin B1 so that count(bins >= B1) >= 2000, count(bins > B1) < 2000
__global__ __launch_bounds__(256) void k_scanhist(const u32* __restrict__ hist, u32* __restrict__ misc) {
    __shared__ u32 csum[256];
    __shared__ u32 cb[256];
    __shared__ int s_cidx;
    __shared__ u32 s_cacc;
    int t = threadIdx.x;
    u32 sum = 0;
    const uint4* h4 = (const uint4*)(hist + t * 256);
    for (int j = 0; j < 64; j++) { uint4 v = h4[j]; sum += v.x + v.y + v.z + v.w; }
    csum[t] = sum;
    __syncthreads();
    if (t == 0) {
        u32 acc = 0;
        int c = 255;
        for (; c > 0; c--) {
            if (acc + csum[c] >= NKEEP) break;
            acc += csum[c];
        }
        s_cidx = c;
        s_cacc = acc;
    }
    __syncthreads();
    cb[t] = hist[s_cidx * 256 + t];
    __syncthreads();
    if (t == 0) {
        u32 acc = s_cacc;
        int b = 255;
        for (; b > 0; b--) {
            acc += cb[b];
            if (acc >= NKEEP) break;
        }
        misc[1] = (u32)(s_cidx * 256 + b);
    }
}

__global__ __launch_bounds__(256) void k_compact(const float* __restrict__ scores, u32* __restrict__ misc,
                                                 u64* __restrict__ keys) {
    int idx = blockIdx.x * 256 + threadIdx.x;
    if (idx >= A_TOTAL) return;
    u32 bits = __float_as_uint(scores[idx]);
    if ((bits >> 16) >= misc[1]) {
        u32 slot = atomicAdd(&misc[0], 1u);
        if (slot < SORTN) keys[slot] = ((u64)bits << 32) | (u64)(~(u32)idx);
    }
}

// bitonic sort 4096 keys DESC (score desc, index asc), then gather cand rows + init suppression words
__global__ __launch_bounds__(1024) void k_sort(const u64* __restrict__ keys, const float* __restrict__ boxes,
                                               float* __restrict__ cand5, u64* __restrict__ suppws) {
    __shared__ u64 lk[SORTN];
    int t = threadIdx.x;
#pragma unroll
    for (int r = 0; r < 4; r++) lk[r * 1024 + t] = keys[r * 1024 + t];
    for (int kk = 2; kk <= SORTN; kk <<= 1) {
        for (int jj = kk >> 1; jj > 0; jj >>= 1) {
            __syncthreads();
#pragma unroll
            for (int rep = 0; rep < 4; rep++) {
                int i = rep * 1024 + t;
                int ixj = i ^ jj;
                if (ixj > i) {
                    u64 a = lk[i], b = lk[ixj];
                    bool sw = ((i & kk) == 0) ? (a < b) : (a > b);  // descending overall
                    if (sw) { lk[i] = b; lk[ixj] = a; }
                }
            }
        }
    }
    __syncthreads();
#pragma unroll
    for (int rep = 0; rep < 2; rep++) {
        int i = rep * 1024 + t;
        bool suppb = true;
        float c0 = 0.f, c1 = 0.f, c2 = 0.f, c3 = 0.f, cs = 0.f;
        if (i < NKEEP) {
            u64 key = lk[i];
            u32 idx = ~(u32)(key & 0xFFFFFFFFull);
            cs = __uint_as_float((u32)(key >> 32));
            c0 = boxes[(size_t)idx * 4 + 0];
            c1 = boxes[(size_t)idx * 4 + 1];
            c2 = boxes[(size_t)idx * 4 + 2];
            c3 = boxes[(size_t)idx * 4 + 3];
            bool valid = ((c2 - c0) >= 16.f) && ((c3 - c1) >= 16.f) && (cs >= 0.05f);
            suppb = !valid;
        }
        cand5[i * 5 + 0] = c0;
        cand5[i * 5 + 1] = c1;
        cand5[i * 5 + 2] = c2;
        cand5[i * 5 + 3] = c3;
        cand5[i * 5 + 4] = cs;
        u64 bal = __ballot(suppb ? 1 : 0);
        if ((t & 63) == 0) suppws[i >> 6] = bal;
    }
}

// IoU > 0.7 bitmask, 64x64 tiles
__global__ __launch_bounds__(64) void k_mask(const float* __restrict__ cand5, u64* __restrict__ mask) {
    __shared__ float cb[64][5];
    int t = threadIdx.x;
    int bi = blockIdx.y, bj = blockIdx.x;
    int j = bj * 64 + t;
    {
        float b0 = cand5[j * 5 + 0], b1v = cand5[j * 5 + 1], b2v = cand5[j * 5 + 2], b3v = cand5[j * 5 + 3];
        cb[t][0] = b0; cb[t][1] = b1v; cb[t][2] = b2v; cb[t][3] = b3v;
        cb[t][4] = (b2v - b0) * (b3v - b1v);
    }
    __syncthreads();
    int i = bi * 64 + t;
    float r0 = cand5[i * 5 + 0], r1 = cand5[i * 5 + 1], r2 = cand5[i * 5 + 2], r3 = cand5[i * 5 + 3];
    float ra = (r2 - r0) * (r3 - r1);
    u64 bits = 0ull;
#pragma unroll 4
    for (int c = 0; c < 64; c++) {
        float lx = fmaxf(r0, cb[c][0]);
        float ly = fmaxf(r1, cb[c][1]);
        float rx = fminf(r2, cb[c][2]);
        float ry = fminf(r3, cb[c][3]);
        float w = fmaxf(rx - lx, 0.f);
        float h = fmaxf(ry - ly, 0.f);
        float inter = w * h;
        float iou = inter / fmaxf(ra + cb[c][4] - inter, 1e-6f);
        if (iou > 0.7f) bits |= (1ull << c);
    }
    mask[(size_t)i * 32 + bj] = bits;
}

// single-wave greedy NMS scan with depth-8 prefetch; writes first <=300 kept rows
__global__ __launch_bounds__(64) void k_scan(const u64* __restrict__ mask, const float* __restrict__ cand5,
                                             const u64* __restrict__ suppws, float* __restrict__ out) {
    int lane = threadIdx.x;
    u64 supp = (lane < 32) ? suppws[lane] : 0ull;
    u64 bufA[8], bufB[8];
    float dA[8], dB[8];
#pragma unroll
    for (int k = 0; k < 8; k++) {
        bufA[k] = (lane < 32) ? mask[(size_t)k * 32 + lane] : 0ull;
        dA[k] = (lane < 5) ? cand5[k * 5 + lane] : 0.f;
    }
    int kcount = 0;
    for (int g = 0; g < 256; g++) {
        int base = g * 8;
        if (g < 255) {
            int nb = base + 8;
#pragma unroll
            for (int k = 0; k < 8; k++) {
                bufB[k] = (lane < 32) ? mask[(size_t)(nb + k) * 32 + lane] : 0ull;
                dB[k] = (lane < 5) ? cand5[(nb + k) * 5 + lane] : 0.f;
            }
        }
        int w = g >> 3;
        u64 cur = __shfl(supp, w);
#pragma unroll
        for (int k = 0; k < 8; k++) {
            int i = base + k;
            if (i < NKEEP && !((cur >> (i & 63)) & 1ull)) {
                if (kcount < NTOPK) {
                    if (lane < 5) out[kcount * 5 + lane] = dA[k];
                    kcount++;
                }
                supp |= bufA[k];
                cur |= __shfl(bufA[k], w);
            }
        }
        if (kcount >= NTOPK) return;
#pragma unroll
        for (int k = 0; k < 8; k++) { bufA[k] = bufB[k]; dA[k] = dB[k]; }
    }
}

extern "C" void kernel_launch(void* const* d_in, const int* in_sizes, int n_in,
                              void* d_out, int out_size, void* d_ws, size_t ws_size,
                              hipStream_t stream) {
    (void)in_sizes; (void)n_in; (void)out_size; (void)ws_size;
    const float* fx = (const float*)d_in[0];
    const float* w1 = (const float*)d_in[1];
    const float* b1 = (const float*)d_in[2];
    const float* w2 = (const float*)d_in[3];
    const float* b2 = (const float*)d_in[4];
    const float* w3 = (const float*)d_in[5];
    const float* b3 = (const float*)d_in[6];
    const int* imh = (const int*)d_in[7];
    const int* imw = (const int*)d_in[8];

    char* ws = (char*)d_ws;
    float*  x      = (float*)(ws + OFF_X);
    double* pox    = (double*)(ws + OFF_POX);
    float*  boxes  = (float*)(ws + OFF_BOXES);
    float*  scores = (float*)(ws + OFF_SCORES);
    u32*    hist   = (u32*)(ws + OFF_HIST);
    u64*    keys   = (u64*)(ws + OFF_KEYS);
    float*  cand5  = (float*)(ws + OFF_CAND5);
    u64*    mask   = (u64*)(ws + OFF_MASK);
    u32*    misc   = (u32*)(ws + OFF_MISC);
    u64*    suppws = (u64*)(ws + OFF_MISC + 64);
    float*  out    = (float*)d_out;

    k_init<<<256, 256, 0, stream>>>(hist, keys, misc, out);
    k_conv1<<<dim3(8, 64), 256, 0, stream>>>(fx, w1, b1, x);
    k_conv23<<<dim3(64, 4), 256, 0, stream>>>(x, w2, w3, pox);
    k_boxes<<<192, 256, 0, stream>>>(pox, b2, b3, imh, imw, boxes, scores, hist);
    k_scanhist<<<1, 256, 0, stream>>>(hist, misc);
    k_compact<<<192, 256, 0, stream>>>(scores, misc, keys);
    k_sort<<<1, 1024, 0, stream>>>(keys, boxes, cand5, suppws);
    k_mask<<<dim3(32, 32), 64, 0, stream>>>(cand5, mask);
    k_scan<<<1, 64, 0, stream>>>(mask, cand5, suppws, out);
}

// Round 6
// 615.553 us; speedup vs baseline: 2.1229x; 1.2907x over previous
//
#include <hip/hip_runtime.h>
#include <math.h>

typedef unsigned int u32;
typedef unsigned long long u64;
typedef unsigned short u16;

typedef float f32x16 __attribute__((ext_vector_type(16)));
typedef short bf16x8 __attribute__((ext_vector_type(8)));

#define A_TOTAL 49152
#define NKEEP 2000
#define NTOPK 300
#define SORTN 4096

// ws layout (bytes)
#define OFF_PACC   0u            // [2][512][4096] f32 = 16,777,216 ; pacc0 becomes x after k_comb
#define OFF_POX    8388608u      // overlays pacc1 (dead after k_comb): 60*4*4096 f64 = 7,864,320
#define OFF_BOXES  16777216u     // 49152*4 f32
#define OFF_SCORES 17563648u     // 49152 f32
#define OFF_HIST   17760256u     // 65536 u32
#define OFF_KEYS   18022400u     // 4096 u64
#define OFF_CAND5  18055168u     // 2048*5 f32
#define OFF_MASK   18096128u     // 2048*32 u64
#define OFF_MISC   18620416u     // [0]=counter,[1]=B1 ; +64B: suppws u64[32]

__global__ __launch_bounds__(256) void k_init(u32* __restrict__ hist, u64* __restrict__ keys,
                                              u32* __restrict__ misc, float* __restrict__ out) {
    int t = blockIdx.x * 256 + threadIdx.x;
    if (t < 65536) hist[t] = 0u;
    if (t < SORTN) keys[t] = 0ull;
    if (t < NTOPK * 5) out[t] = 0.f;
    if (t == 0) misc[0] = 0u;
}

// ---------- bf16 split helpers ----------
__device__ __forceinline__ u16 f2bf(float v) {
    u32 u = __float_as_uint(v);
    return (u16)((u + 0x7FFFu + ((u >> 16) & 1u)) >> 16);
}
__device__ __forceinline__ float bf2f(u16 h) { return __uint_as_float(((u32)h) << 16); }
__device__ __forceinline__ void split3(float v, u16& h, u16& m, u16& l) {
    h = f2bf(v);
    float r1 = v - bf2f(h);
    m = f2bf(r1);
    float r2 = r1 - bf2f(m);
    l = f2bf(r2);
}
__device__ __forceinline__ bf16x8 ldsfrag(const u16* base, int byteoff) {
    const u64* p = (const u64*)((const char*)base + byteoff);
    union { u64 q[2]; bf16x8 v; } x;
    x.q[0] = p[0];
    x.q[1] = p[1];
    return x.v;
}

// conv1 via MFMA bf16x3 splits, 6 product terms, f32 MFMA accum + f64 drain every 3 taps.
// C[co,px] = sum_k W[co,k] * X[k,px], k = tap*1024 + ci (tap-major: K16 step = 16 consecutive ci).
// Block: 512 thr = 8 waves (4 co-grp x 2 px-grp); tile 128co x 128px (8y x 16x); K-split x2 (blockIdx.z).
// LDS: sA [3t][128co][52] (3 taps x 16 ci + pad), sB [3t][180 halo][20] (16 ci + pad), splits on the fly.
// Reg-prefetch next round's w1/fx gathers during MFMA compute (R2/R5-validated pattern).
__global__ __launch_bounds__(512) void k_conv1m(const float* __restrict__ fx, const float* __restrict__ w1,
                                                float* __restrict__ pacc) {
    __shared__ u16 sA[3 * 6656];   // t-stride 6656 u16 = 13312 B; co row 52 u16 = 104 B
    __shared__ u16 sB[3 * 3600];   // t-stride 3600 u16 = 7200 B;  loc row 20 u16 = 40 B
    const int tid = threadIdx.x;
    const int lane = tid & 63;
    const int wid = tid >> 6;       // 0..7
    const int cgw = wid >> 1;       // 0..3 -> co offset 32*cgw
    const int pgw = wid & 1;        // 0..1 -> py offset 4*pgw
    const int n = lane & 31;        // operand row/col index
    const int g = lane >> 5;        // k-group (0/1)
    const int bpx = blockIdx.x;     // 0..31
    const int y0 = (bpx >> 2) * 8, x0 = (bpx & 3) * 16;
    const int co0 = blockIdx.y * 128;
    const int kh = blockIdx.z;      // 0..1
    const int ci_base = kh * 512;

    // ---- staging descriptors (chunk/round-invariant) ----
    int wg0[12], wl[12];
#pragma unroll
    for (int j = 0; j < 12; j++) {
        int idx = tid + j * 512;             // 0..6143 = 128co x 3tap x 16ci
        int co = idx / 48, rem = idx - co * 48;
        int tapr = rem >> 4, ci = rem & 15;
        wg0[j] = (co0 + co) * 9216 + ci * 9 + tapr;   // + (ci_base + c*16)*9 + r*3 at load
        wl[j] = co * 52 + tapr * 16 + ci;
    }
    int fg0[6], fl[6];
#pragma unroll
    for (int j = 0; j < 6; j++) {
        int idx = tid + j * 512;             // 0..3071, valid < 2880 = 16ci x 10hy x 18hx
        bool wr = idx < 2880;
        int ci = idx / 180, rem = idx - ci * 180;
        int hy = rem / 18, hx = rem - hy * 18;
        int gy = y0 + hy - 1, gx = x0 + hx - 1;
        bool ok = wr && gy >= 0 && gy < 64 && gx >= 0 && gx < 64;
        fg0[j] = ok ? (ci * 4096 + gy * 64 + gx) : -1;
        fl[j] = wr ? (rem * 20 + ci) : -1;
    }

    f32x16 acc[2];
    double accD[2][16];
#pragma unroll
    for (int pb = 0; pb < 2; pb++)
#pragma unroll
        for (int i = 0; i < 16; i++) { acc[pb][i] = 0.f; accD[pb][i] = 0.0; }

    float pw[12], pf[6];
    {   // prologue prefetch: chunk 0, round 0
        const float* wp = w1 + (size_t)ci_base * 9;
#pragma unroll
        for (int j = 0; j < 12; j++) pw[j] = wp[wg0[j]];
        const float* fp = fx + (size_t)ci_base * 4096;
#pragma unroll
        for (int j = 0; j < 6; j++) pf[j] = (fg0[j] >= 0) ? fp[fg0[j]] : 0.f;
    }

#pragma unroll 1
    for (int c = 0; c < 32; c++) {
#pragma unroll
        for (int r = 0; r < 3; r++) {        // round r covers taps {3r..3r+2}: dy = r, dx = tapr
            __syncthreads();                 // previous round's frag reads done
#pragma unroll
            for (int j = 0; j < 12; j++) {
                u16 h, m, l;
                split3(pw[j], h, m, l);
                sA[wl[j]] = h; sA[6656 + wl[j]] = m; sA[13312 + wl[j]] = l;
            }
            if (r == 0) {
#pragma unroll
                for (int j = 0; j < 6; j++) {
                    if (fl[j] >= 0) {
                        u16 h, m, l;
                        split3(pf[j], h, m, l);
                        sB[fl[j]] = h; sB[3600 + fl[j]] = m; sB[7200 + fl[j]] = l;
                    }
                }
            }
            __syncthreads();
            if (!(c == 31 && r == 2)) {      // prefetch next round (lands under MFMA compute)
                int c2 = (r == 2) ? c + 1 : c;
                int r2 = (r == 2) ? 0 : r + 1;
                const float* wp = w1 + (size_t)(ci_base + c2 * 16) * 9 + r2 * 3;
#pragma unroll
                for (int j = 0; j < 12; j++) pw[j] = wp[wg0[j]];
                if (r == 2) {
                    const float* fp = fx + (size_t)(ci_base + (c + 1) * 16) * 4096;
#pragma unroll
                    for (int j = 0; j < 6; j++) pf[j] = (fg0[j] >= 0) ? fp[fg0[j]] : 0.f;
                }
            }
            // compute: 3 taps (dx = 0..2), dy = r
#pragma unroll
            for (int dx = 0; dx < 3; dx++) {
                bf16x8 a[3], b[2][3];
#pragma unroll
                for (int t = 0; t < 3; t++)
                    a[t] = ldsfrag(sA, t * 13312 + (cgw * 32 + n) * 104 + dx * 32 + g * 16);
#pragma unroll
                for (int pb = 0; pb < 2; pb++) {
                    int hy = pgw * 4 + pb * 2 + (n >> 4) + r;
                    int hx = (n & 15) + dx;
                    int loc = hy * 18 + hx;
#pragma unroll
                    for (int t = 0; t < 3; t++)
                        b[pb][t] = ldsfrag(sB, t * 7200 + loc * 40 + g * 16);
                }
#pragma unroll
                for (int pb = 0; pb < 2; pb++) {
                    acc[pb] = __builtin_amdgcn_mfma_f32_32x32x16_bf16(a[0], b[pb][0], acc[pb], 0, 0, 0);
                    acc[pb] = __builtin_amdgcn_mfma_f32_32x32x16_bf16(a[0], b[pb][1], acc[pb], 0, 0, 0);
                    acc[pb] = __builtin_amdgcn_mfma_f32_32x32x16_bf16(a[1], b[pb][0], acc[pb], 0, 0, 0);
                    acc[pb] = __builtin_amdgcn_mfma_f32_32x32x16_bf16(a[0], b[pb][2], acc[pb], 0, 0, 0);
                    acc[pb] = __builtin_amdgcn_mfma_f32_32x32x16_bf16(a[1], b[pb][1], acc[pb], 0, 0, 0);
                    acc[pb] = __builtin_amdgcn_mfma_f32_32x32x16_bf16(a[2], b[pb][0], acc[pb], 0, 0, 0);
                }
            }
            // drain f32 acc -> f64 every round (keeps f32-chain error ~1e-7)
#pragma unroll
            for (int pb = 0; pb < 2; pb++)
#pragma unroll
                for (int i = 0; i < 16; i++) { accD[pb][i] += (double)acc[pb][i]; acc[pb][i] = 0.f; }
        }
    }

    // epilogue: C/D layout 32x32: col = lane&31, row = (reg&3) + 8*(reg>>2) + 4*(lane>>5)
    const int row_hi = 4 * g;
#pragma unroll
    for (int pb = 0; pb < 2; pb++) {
        int py = pgw * 4 + pb * 2 + (n >> 4);
        int gp = (y0 + py) * 64 + x0 + (n & 15);
#pragma unroll
        for (int rg = 0; rg < 16; rg++) {
            int co = co0 + cgw * 32 + (rg & 3) + 8 * (rg >> 2) + row_hi;
            pacc[(size_t)kh * 2097152 + (size_t)co * 4096 + gp] = (float)accD[pb][rg];
        }
    }
}

// x = relu(f64(pacc0) + f64(pacc1) + bias), written in place over pacc0
__global__ __launch_bounds__(256) void k_comb(float* __restrict__ x, const float* __restrict__ p1,
                                              const float* __restrict__ b1) {
    int i = blockIdx.x * 256 + threadIdx.x;   // grid 8192 = 2M
    double v = (double)x[i] + (double)p1[i] + (double)b1[i >> 12];
    x[i] = fmaxf((float)v, 0.f);
}

// 1x1 convs, LDS-tiled, ci-quarter partials (f64), bias added later in k_boxes.
__global__ __launch_bounds__(256) void k_conv23(const float* __restrict__ x,
                                                const float* __restrict__ w2, const float* __restrict__ w3,
                                                double* __restrict__ pox) {
    __shared__ float xs[32 * 64];     // [ci][px]
    __shared__ float wsh[60 * 128];   // [o][ci]
    const int tid = threadIdx.x;
    const int px0 = blockIdx.x * 64;
    const int cib = blockIdx.y * 128;
    const int px = tid & 63;
    const int og = tid >> 6;          // 0..3 -> o = og*15 + j

#pragma unroll
    for (int k = 0; k < 30; k++) {
        int e = tid + k * 256;
        int o = e >> 7, ci = e & 127;
        float wv = (o < 12) ? w2[o * 512 + cib + ci] : w3[(size_t)(o - 12) * 512 + cib + ci];
        wsh[o * 128 + ci] = wv;
    }

    double acc[15];
#pragma unroll
    for (int j = 0; j < 15; j++) acc[j] = 0.0;

#pragma unroll 1
    for (int ch = 0; ch < 4; ch++) {
        __syncthreads();
#pragma unroll
        for (int k = 0; k < 8; k++) {
            int e = tid + k * 256;
            int ci = e >> 6, p = e & 63;
            xs[ci * 64 + p] = x[(size_t)(cib + ch * 32 + ci) * 4096 + px0 + p];
        }
        __syncthreads();
#pragma unroll 1
        for (int ci = 0; ci < 32; ci++) {
            double xd = (double)xs[ci * 64 + px];
            const float* wrow = &wsh[ch * 32 + ci];
#pragma unroll
            for (int j = 0; j < 15; j++)
                acc[j] = fma(xd, (double)wrow[(og * 15 + j) * 128], acc[j]);
        }
    }
#pragma unroll
    for (int j = 0; j < 15; j++) {
        int o = og * 15 + j;
        pox[((size_t)o * 4 + blockIdx.y) * 4096 + px0 + px] = acc[j];
    }
}

// decode: combine ci-quarter partials (+bias, round f32), f64 sigmoid/box decode, histogram
__global__ __launch_bounds__(256) void k_boxes(const double* __restrict__ pox,
                                               const float* __restrict__ b2, const float* __restrict__ b3,
                                               const int* __restrict__ imh, const int* __restrict__ imw,
                                               float* __restrict__ boxes, float* __restrict__ scores,
                                               u32* __restrict__ hist) {
    int idx = blockIdx.x * 256 + threadIdx.x;
    if (idx >= A_TOTAL) return;
    int px = idx / 12, a = idx - px * 12;

    double t = 0.0;
#pragma unroll
    for (int q = 0; q < 4; q++) t += pox[((size_t)a * 4 + q) * 4096 + px];
    float o = (float)(t + (double)b2[a]);
    float s = (float)(1.0 / (1.0 + exp(-(double)o)));
    scores[idx] = s;
    atomicAdd(&hist[__float_as_uint(s) >> 16], 1u);

    float d[4];
#pragma unroll
    for (int c = 0; c < 4; c++) {
        int oo = 12 + a * 4 + c;
        double u = 0.0;
#pragma unroll
        for (int q = 0; q < 4; q++) u += pox[((size_t)oo * 4 + q) * 4096 + px];
        d[c] = (float)(u + (double)b3[a * 4 + c]);
    }

    int py = px >> 6, pxx = px & 63;
    double cx = pxx * 16.0 + 8.0, cy = py * 16.0 + 8.0;
    int si = a / 3, ri = a - si * 3;
    double scale = (double)(32 << si);
    double ratio = 0.5 * (double)(1 << ri);
    double sq = sqrt(ratio);
    double aw = scale * sq, ah = scale / sq;
    double xc = cx + (double)d[0] * aw;
    double yc = cy + (double)d[1] * ah;
    double wv = aw * exp((double)d[2]);
    double hv = ah * exp((double)d[3]);
    float W = (float)imw[0], H = (float)imh[0];
    float x1 = fminf(fmaxf((float)(xc - wv * 0.5), 0.f), W);
    float x2 = fminf(fmaxf((float)(xc + wv * 0.5), 0.f), W);
    float y1 = fminf(fmaxf((float)(yc - hv * 0.5), 0.f), H);
    float y2 = fminf(fmaxf((float)(yc + hv * 0.5), 0.f), H);
    boxes[(size_t)idx * 4 + 0] = x1;
    boxes[(size_t)idx * 4 + 1] = y1;
    boxes[(size_t)idx * 4 + 2] = x2;
    boxes[(size_t)idx * 4 + 3] = y2;
}

// find boundary bin B1 so that count(bins >= B1) >= 2000, count(bins > B1) < 2000
__global__ __launch_bounds__(256) void k_scanhist(const u32* __restrict__ hist, u32* __restrict__ misc) {
    __shared__ u32 csum[256];
    __shared__ u32 cb[256];
    __shared__ int s_cidx;
    __shared__ u32 s_cacc;
    int t = threadIdx.x;
    u32 sum = 0;
    const uint4* h4 = (const uint4*)(hist + t * 256);
    for (int j = 0; j < 64; j++) { uint4 v = h4[j]; sum += v.x + v.y + v.z + v.w; }
    csum[t] = sum;
    __syncthreads();
    if (t == 0) {
        u32 acc = 0;
        int c = 255;
        for (; c > 0; c--) {
            if (acc + csum[c] >= NKEEP) break;
            acc += csum[c];
        }
        s_cidx = c;
        s_cacc = acc;
    }
    __syncthreads();
    cb[t] = hist[s_cidx * 256 + t];
    __syncthreads();
    if (t == 0) {
        u32 acc = s_cacc;
        int b = 255;
        for (; b > 0; b--) {
            acc += cb[b];
            if (acc >= NKEEP) break;
        }
        misc[1] = (u32)(s_cidx * 256 + b);
    }
}

__global__ __launch_bounds__(256) void k_compact(const float* __restrict__ scores, u32* __restrict__ misc,
                                                 u64* __restrict__ keys) {
    int idx = blockIdx.x * 256 + threadIdx.x;
    if (idx >= A_TOTAL) return;
    u32 bits = __float_as_uint(scores[idx]);
    if ((bits >> 16) >= misc[1]) {
        u32 slot = atomicAdd(&misc[0], 1u);
        if (slot < SORTN) keys[slot] = ((u64)bits << 32) | (u64)(~(u32)idx);
    }
}

// bitonic sort 4096 keys DESC (score desc, index asc), gather cand rows + init suppression words
__global__ __launch_bounds__(1024) void k_sort(const u64* __restrict__ keys, const float* __restrict__ boxes,
                                               float* __restrict__ cand5, u64* __restrict__ suppws) {
    __shared__ u64 lk[SORTN];
    int t = threadIdx.x;
#pragma unroll
    for (int r = 0; r < 4; r++) lk[r * 1024 + t] = keys[r * 1024 + t];
    for (int kk = 2; kk <= SORTN; kk <<= 1) {
        for (int jj = kk >> 1; jj > 0; jj >>= 1) {
            __syncthreads();
#pragma unroll
            for (int rep = 0; rep < 4; rep++) {
                int i = rep * 1024 + t;
                int ixj = i ^ jj;
                if (ixj > i) {
                    u64 a = lk[i], b = lk[ixj];
                    bool sw = ((i & kk) == 0) ? (a < b) : (a > b);
                    if (sw) { lk[i] = b; lk[ixj] = a; }
                }
            }
        }
    }
    __syncthreads();
#pragma unroll
    for (int rep = 0; rep < 2; rep++) {
        int i = rep * 1024 + t;
        bool suppb = true;
        float c0 = 0.f, c1 = 0.f, c2 = 0.f, c3 = 0.f, cs = 0.f;
        if (i < NKEEP) {
            u64 key = lk[i];
            u32 idx = ~(u32)(key & 0xFFFFFFFFull);
            cs = __uint_as_float((u32)(key >> 32));
            c0 = boxes[(size_t)idx * 4 + 0];
            c1 = boxes[(size_t)idx * 4 + 1];
            c2 = boxes[(size_t)idx * 4 + 2];
            c3 = boxes[(size_t)idx * 4 + 3];
            bool valid = ((c2 - c0) >= 16.f) && ((c3 - c1) >= 16.f) && (cs >= 0.05f);
            suppb = !valid;
        }
        cand5[i * 5 + 0] = c0;
        cand5[i * 5 + 1] = c1;
        cand5[i * 5 + 2] = c2;
        cand5[i * 5 + 3] = c3;
        cand5[i * 5 + 4] = cs;
        u64 bal = __ballot(suppb ? 1 : 0);
        if ((t & 63) == 0) suppws[i >> 6] = bal;
    }
}

// IoU > 0.7 bitmask, 64x64 tiles
__global__ __launch_bounds__(64) void k_mask(const float* __restrict__ cand5, u64* __restrict__ mask) {
    __shared__ float cb[64][5];
    int t = threadIdx.x;
    int bi = blockIdx.y, bj = blockIdx.x;
    int j = bj * 64 + t;
    {
        float b0 = cand5[j * 5 + 0], b1v = cand5[j * 5 + 1], b2v = cand5[j * 5 + 2], b3v = cand5[j * 5 + 3];
        cb[t][0] = b0; cb[t][1] = b1v; cb[t][2] = b2v; cb[t][3] = b3v;
        cb[t][4] = (b2v - b0) * (b3v - b1v);
    }
    __syncthreads();
    int i = bi * 64 + t;
    float r0 = cand5[i * 5 + 0], r1 = cand5[i * 5 + 1], r2 = cand5[i * 5 + 2], r3 = cand5[i * 5 + 3];
    float ra = (r2 - r0) * (r3 - r1);
    u64 bits = 0ull;
#pragma unroll 4
    for (int c = 0; c < 64; c++) {
        float lx = fmaxf(r0, cb[c][0]);
        float ly = fmaxf(r1, cb[c][1]);
        float rx = fminf(r2, cb[c][2]);
        float ry = fminf(r3, cb[c][3]);
        float w = fmaxf(rx - lx, 0.f);
        float h = fmaxf(ry - ly, 0.f);
        float inter = w * h;
        float iou = inter / fmaxf(ra + cb[c][4] - inter, 1e-6f);
        if (iou > 0.7f) bits |= (1ull << c);
    }
    mask[(size_t)i * 32 + bj] = bits;
}

// single-wave greedy NMS scan with depth-8 prefetch; writes first <=300 kept rows
__global__ __launch_bounds__(64) void k_scan(const u64* __restrict__ mask, const float* __restrict__ cand5,
                                             const u64* __restrict__ suppws, float* __restrict__ out) {
    int lane = threadIdx.x;
    u64 supp = (lane < 32) ? suppws[lane] : 0ull;
    u64 bufA[8], bufB[8];
    float dA[8], dB[8];
#pragma unroll
    for (int k = 0; k < 8; k++) {
        bufA[k] = (lane < 32) ? mask[(size_t)k * 32 + lane] : 0ull;
        dA[k] = (lane < 5) ? cand5[k * 5 + lane] : 0.f;
    }
    int kcount = 0;
    for (int gq = 0; gq < 256; gq++) {
        int base = gq * 8;
        if (gq < 255) {
            int nb = base + 8;
#pragma unroll
            for (int k = 0; k < 8; k++) {
                bufB[k] = (lane < 32) ? mask[(size_t)(nb + k) * 32 + lane] : 0ull;
                dB[k] = (lane < 5) ? cand5[(nb + k) * 5 + lane] : 0.f;
            }
        }
        int w = gq >> 3;
        u64 cur = __shfl(supp, w);
#pragma unroll
        for (int k = 0; k < 8; k++) {
            int i = base + k;
            if (i < NKEEP && !((cur >> (i & 63)) & 1ull)) {
                if (kcount < NTOPK) {
                    if (lane < 5) out[kcount * 5 + lane] = dA[k];
                    kcount++;
                }
                supp |= bufA[k];
                cur |= __shfl(bufA[k], w);
            }
        }
        if (kcount >= NTOPK) return;
#pragma unroll
        for (int k = 0; k < 8; k++) { bufA[k] = bufB[k]; dA[k] = dB[k]; }
    }
}

extern "C" void kernel_launch(void* const* d_in, const int* in_sizes, int n_in,
                              void* d_out, int out_size, void* d_ws, size_t ws_size,
                              hipStream_t stream) {
    (void)in_sizes; (void)n_in; (void)out_size; (void)ws_size;
    const float* fx = (const float*)d_in[0];
    const float* w1 = (const float*)d_in[1];
    const float* b1 = (const float*)d_in[2];
    const float* w2 = (const float*)d_in[3];
    const float* b2 = (const float*)d_in[4];
    const float* w3 = (const float*)d_in[5];
    const float* b3 = (const float*)d_in[6];
    const int* imh = (const int*)d_in[7];
    const int* imw = (const int*)d_in[8];

    char* ws = (char*)d_ws;
    float*  pacc   = (float*)(ws + OFF_PACC);   // [2][512][4096]; pacc0 becomes x
    double* pox    = (double*)(ws + OFF_POX);
    float*  boxes  = (float*)(ws + OFF_BOXES);
    float*  scores = (float*)(ws + OFF_SCORES);
    u32*    hist   = (u32*)(ws + OFF_HIST);
    u64*    keys   = (u64*)(ws + OFF_KEYS);
    float*  cand5  = (float*)(ws + OFF_CAND5);
    u64*    mask   = (u64*)(ws + OFF_MASK);
    u32*    misc   = (u32*)(ws + OFF_MISC);
    u64*    suppws = (u64*)(ws + OFF_MISC + 64);
    float*  out    = (float*)d_out;

    k_init<<<256, 256, 0, stream>>>(hist, keys, misc, out);
    k_conv1m<<<dim3(32, 4, 2), 512, 0, stream>>>(fx, w1, pacc);
    k_comb<<<8192, 256, 0, stream>>>(pacc, pacc + 2097152, b1);
    k_conv23<<<dim3(64, 4), 256, 0, stream>>>(pacc, w2, w3, pox);
    k_boxes<<<192, 256, 0, stream>>>(pox, b2, b3, imh, imw, boxes, scores, hist);
    k_scanhist<<<1, 256, 0, stream>>>(hist, misc);
    k_compact<<<192, 256, 0, stream>>>(scores, misc, keys);
    k_sort<<<1, 1024, 0, stream>>>(keys, boxes, cand5, suppws);
    k_mask<<<dim3(32, 32), 64, 0, stream>>>(cand5, mask);
    k_scan<<<1, 64, 0, stream>>>(mask, cand5, suppws, out);
}

// Round 7
// 560.769 us; speedup vs baseline: 2.3303x; 1.0977x over previous
//
#include <hip/hip_runtime.h>
#include <math.h>

typedef unsigned int u32;
typedef unsigned long long u64;
typedef unsigned short u16;

typedef float f32x16 __attribute__((ext_vector_type(16)));
typedef short bf16x8 __attribute__((ext_vector_type(8)));

#define A_TOTAL 49152
#define NKEEP 2000
#define NTOPK 300
#define SORTN 4096

// ws layout (bytes)
#define OFF_PACC   0u            // [2][512][4096] f32 = 16,777,216 ; pacc0 becomes x after k_comb
#define OFF_POX    8388608u      // overlays pacc1 (dead after k_comb): 60*4*4096 f64 = 7,864,320
#define OFF_BOXES  16777216u     // 49152*4 f32
#define OFF_SCORES 17563648u     // 49152 f32
#define OFF_HIST   17760256u     // 65536 u32
#define OFF_KEYS   18022400u     // 4096 u64
#define OFF_CAND5  18055168u     // 2048*5 f32
#define OFF_MASK   18096128u     // 2048*32 u64
#define OFF_MISC   18620416u     // [0]=counter,[1]=B1 ; +64B: suppws u64[32]

__global__ __launch_bounds__(256) void k_init(u32* __restrict__ hist, u64* __restrict__ keys,
                                              u32* __restrict__ misc, float* __restrict__ out) {
    int t = blockIdx.x * 256 + threadIdx.x;
    if (t < 65536) hist[t] = 0u;
    if (t < SORTN) keys[t] = 0ull;
    if (t < NTOPK * 5) out[t] = 0.f;
    if (t == 0) misc[0] = 0u;
}

// ---------- bf16 split helpers ----------
__device__ __forceinline__ u16 f2bf(float v) {
    u32 u = __float_as_uint(v);
    return (u16)((u + 0x7FFFu + ((u >> 16) & 1u)) >> 16);
}
__device__ __forceinline__ float bf2f(u16 h) { return __uint_as_float(((u32)h) << 16); }
__device__ __forceinline__ void split3(float v, u16& h, u16& m, u16& l) {
    h = f2bf(v);
    float r1 = v - bf2f(h);
    m = f2bf(r1);
    float r2 = r1 - bf2f(m);
    l = f2bf(r2);
}
__device__ __forceinline__ bf16x8 ldsfrag(const u16* p) {
    const u64* q = (const u64*)p;
    union { u64 w[2]; bf16x8 v; } x;
    x.w[0] = q[0];
    x.w[1] = q[1];
    return x.v;
}

// conv1 via MFMA bf16x3 splits (6 terms), f32 MFMA accum + f64 drain every 3 taps (R6-validated
// error profile). C[co,px] = sum_k W[co,k]*X[k,px], chunk = 16 ci x ALL 9 taps:
//  - W chunk = 144 CONTIGUOUS floats per co row (w1 is [co][ci][tap]) -> 18 coalesced loads/thread
//  - ONE stage phase + 2 barriers per chunk (was 3 phases / 6 barriers in R6)
//  - co-tile 64, px-tile 128, K-split x2 -> grid 32x8x2 = 512 blocks = 2 blocks/CU (TLP overlap)
// LDS: sA [3][64co][148] (k = tap*16+ci, pad->lane stride 74 dw, gcd(74,32)=2: conflict-free),
//      sB [3][180 halo][20] (16ci/loc). 78.4 KB -> 2 blocks/CU; VGPR capped 128 via launch_bounds.
__global__ __launch_bounds__(512, 4) void k_conv1m(const float* __restrict__ fx, const float* __restrict__ w1,
                                                   float* __restrict__ pacc) {
    __shared__ u16 sA[3 * 9472];   // 56832 B ; split t at t*9472 ; row = co*148 + tap*16 + ci
    __shared__ u16 sB[3 * 3600];   // 21600 B ; split t at t*3600 ; row = loc*20 + ci
    const int tid = threadIdx.x;
    const int lane = tid & 63;
    const int wid = tid >> 6;       // 0..7
    const int cgw = wid >> 2;       // 0..1 -> co offset 32*cgw
    const int pgw = wid & 3;        // 0..3 -> px group of 32
    const int n = lane & 31;
    const int g = lane >> 5;        // k-octet
    const int bpx = blockIdx.x;     // 0..31
    const int y0 = (bpx >> 2) * 8, x0 = (bpx & 3) * 16;
    const int co0 = blockIdx.y * 64;
    const int kh = blockIdx.z;      // 0..1
    const int ci_base = kh * 512;

    // ---- W staging descriptors: 18 floats/thread as 9 adjacent pairs, coalesced ----
    int wg[9], wlA[9];
    u32 wbm = 0u;                   // bit j: first float of pair has tap==8 (pair crosses ci)
#pragma unroll
    for (int j = 0; j < 9; j++) {
        int e = tid + j * 512;      // pair id 0..4607 = 64co x 72
        int co = e / 72, q = e - co * 72;
        int f0 = q * 2;
        int t0 = f0 % 9, c0 = f0 / 9;
        wg[j] = co * 9216 + f0;     // + co0*9216 + cb*9 at load (contiguous per co row)
        wlA[j] = co * 148 + t0 * 16 + c0;
        if (t0 == 8) wbm |= (1u << j);
    }
    // ---- fx staging descriptors: 16ci x 10hy x 18hx = 2880, 6/thread ----
    int fg0[6], fl[6];
#pragma unroll
    for (int j = 0; j < 6; j++) {
        int idx = tid + j * 512;
        bool wr = idx < 2880;
        int ci = idx / 180, rem = idx - ci * 180;
        int hy = rem / 18, hx = rem - hy * 18;
        int gy = y0 + hy - 1, gx = x0 + hx - 1;
        bool ok = wr && gy >= 0 && gy < 64 && gx >= 0 && gx < 64;
        fg0[j] = ok ? (ci * 4096 + gy * 64 + gx) : -1;
        fl[j] = wr ? (rem * 20 + ci) : -1;
    }

    f32x16 acc;
    double accD[16];
#pragma unroll
    for (int i = 0; i < 16; i++) { acc[i] = 0.f; accD[i] = 0.0; }

    float pw[18], pf[6];
    {   // prologue: prefetch chunk 0
        const float* wp = w1 + (size_t)co0 * 9216 + (size_t)ci_base * 9;
#pragma unroll
        for (int j = 0; j < 9; j++) { pw[2 * j] = wp[wg[j]]; pw[2 * j + 1] = wp[wg[j] + 1]; }
        const float* fp = fx + (size_t)ci_base * 4096;
#pragma unroll
        for (int j = 0; j < 6; j++) pf[j] = (fg0[j] >= 0) ? fp[fg0[j]] : 0.f;
    }

#pragma unroll 1
    for (int c = 0; c < 32; c++) {
        __syncthreads();            // previous chunk's frag reads done; LDS writable
#pragma unroll
        for (int j = 0; j < 9; j++) {
            u16 h, m, l;
            int iA = wlA[j];
            int iB = iA + (((wbm >> j) & 1u) ? -127 : 16);   // next (ci,tap) in tap-major k
            split3(pw[2 * j], h, m, l);
            sA[iA] = h; sA[9472 + iA] = m; sA[18944 + iA] = l;
            split3(pw[2 * j + 1], h, m, l);
            sA[iB] = h; sA[9472 + iB] = m; sA[18944 + iB] = l;
        }
#pragma unroll
        for (int j = 0; j < 6; j++) {
            if (fl[j] >= 0) {
                u16 h, m, l;
                split3(pf[j], h, m, l);
                sB[fl[j]] = h; sB[3600 + fl[j]] = m; sB[7200 + fl[j]] = l;
            }
        }
        __syncthreads();
        if (c < 31) {               // prefetch chunk c+1; lands under MFMA compute
            const float* wp = w1 + (size_t)co0 * 9216 + (size_t)(ci_base + (c + 1) * 16) * 9;
#pragma unroll
            for (int j = 0; j < 9; j++) { pw[2 * j] = wp[wg[j]]; pw[2 * j + 1] = wp[wg[j] + 1]; }
            const float* fp = fx + (size_t)(ci_base + (c + 1) * 16) * 4096;
#pragma unroll
            for (int j = 0; j < 6; j++) pf[j] = (fg0[j] >= 0) ? fp[fg0[j]] : 0.f;
        }

        // compute: 9 taps; drain f32->f64 every 3 taps (18-MFMA chains, R6 profile)
#pragma unroll 1
        for (int dy = 0; dy < 3; dy++) {
#pragma unroll
            for (int dx = 0; dx < 3; dx++) {
                const int tap = dy * 3 + dx;
                const int aoff = (cgw * 32 + n) * 148 + tap * 16 + g * 8;
                bf16x8 ah = ldsfrag(&sA[aoff]);
                bf16x8 am = ldsfrag(&sA[9472 + aoff]);
                bf16x8 al = ldsfrag(&sA[18944 + aoff]);
                const int loc = (pgw * 2 + (n >> 4) + dy) * 18 + (n & 15) + dx;
                const int boff = loc * 20 + g * 8;
                bf16x8 bh = ldsfrag(&sB[boff]);
                bf16x8 bm = ldsfrag(&sB[3600 + boff]);
                bf16x8 bl = ldsfrag(&sB[7200 + boff]);
                acc = __builtin_amdgcn_mfma_f32_32x32x16_bf16(ah, bh, acc, 0, 0, 0);
                acc = __builtin_amdgcn_mfma_f32_32x32x16_bf16(ah, bm, acc, 0, 0, 0);
                acc = __builtin_amdgcn_mfma_f32_32x32x16_bf16(am, bh, acc, 0, 0, 0);
                acc = __builtin_amdgcn_mfma_f32_32x32x16_bf16(ah, bl, acc, 0, 0, 0);
                acc = __builtin_amdgcn_mfma_f32_32x32x16_bf16(am, bm, acc, 0, 0, 0);
                acc = __builtin_amdgcn_mfma_f32_32x32x16_bf16(al, bh, acc, 0, 0, 0);
            }
#pragma unroll
            for (int i = 0; i < 16; i++) { accD[i] += (double)acc[i]; acc[i] = 0.f; }
        }
    }

    // epilogue: C/D 32x32 layout: col = n (pixel), row = (rg&3) + 8*(rg>>2) + 4*g (co in group)
    {
        int p = pgw * 32 + n;
        int py = p >> 4, pxx = p & 15;
        int gp = (y0 + py) * 64 + x0 + pxx;
        const int row_hi = 4 * g;
#pragma unroll
        for (int rg = 0; rg < 16; rg++) {
            int co = co0 + cgw * 32 + (rg & 3) + 8 * (rg >> 2) + row_hi;
            pacc[(size_t)kh * 2097152 + (size_t)co * 4096 + gp] = (float)accD[rg];
        }
    }
}

// x = relu(f64(pacc0) + f64(pacc1) + bias), written in place over pacc0
__global__ __launch_bounds__(256) void k_comb(float* __restrict__ x, const float* __restrict__ p1,
                                              const float* __restrict__ b1) {
    int i = blockIdx.x * 256 + threadIdx.x;   // grid 8192 = 2M
    double v = (double)x[i] + (double)p1[i] + (double)b1[i >> 12];
    x[i] = fmaxf((float)v, 0.f);
}

// 1x1 convs, LDS-tiled, ci-quarter partials (f64), bias added later in k_boxes.
__global__ __launch_bounds__(256) void k_conv23(const float* __restrict__ x,
                                                const float* __restrict__ w2, const float* __restrict__ w3,
                                                double* __restrict__ pox) {
    __shared__ float xs[32 * 64];     // [ci][px]
    __shared__ float wsh[60 * 128];   // [o][ci]
    const int tid = threadIdx.x;
    const int px0 = blockIdx.x * 64;
    const int cib = blockIdx.y * 128;
    const int px = tid & 63;
    const int og = tid >> 6;          // 0..3 -> o = og*15 + j

#pragma unroll
    for (int k = 0; k < 30; k++) {
        int e = tid + k * 256;
        int o = e >> 7, ci = e & 127;
        float wv = (o < 12) ? w2[o * 512 + cib + ci] : w3[(size_t)(o - 12) * 512 + cib + ci];
        wsh[o * 128 + ci] = wv;
    }

    double acc[15];
#pragma unroll
    for (int j = 0; j < 15; j++) acc[j] = 0.0;

#pragma unroll 1
    for (int ch = 0; ch < 4; ch++) {
        __syncthreads();
#pragma unroll
        for (int k = 0; k < 8; k++) {
            int e = tid + k * 256;
            int ci = e >> 6, p = e & 63;
            xs[ci * 64 + p] = x[(size_t)(cib + ch * 32 + ci) * 4096 + px0 + p];
        }
        __syncthreads();
#pragma unroll 1
        for (int ci = 0; ci < 32; ci++) {
            double xd = (double)xs[ci * 64 + px];
            const float* wrow = &wsh[ch * 32 + ci];
#pragma unroll
            for (int j = 0; j < 15; j++)
                acc[j] = fma(xd, (double)wrow[(og * 15 + j) * 128], acc[j]);
        }
    }
#pragma unroll
    for (int j = 0; j < 15; j++) {
        int o = og * 15 + j;
        pox[((size_t)o * 4 + blockIdx.y) * 4096 + px0 + px] = acc[j];
    }
}

// decode: combine ci-quarter partials (+bias, round f32), f64 sigmoid/box decode, histogram
__global__ __launch_bounds__(256) void k_boxes(const double* __restrict__ pox,
                                               const float* __restrict__ b2, const float* __restrict__ b3,
                                               const int* __restrict__ imh, const int* __restrict__ imw,
                                               float* __restrict__ boxes, float* __restrict__ scores,
                                               u32* __restrict__ hist) {
    int idx = blockIdx.x * 256 + threadIdx.x;
    if (idx >= A_TOTAL) return;
    int px = idx / 12, a = idx - px * 12;

    double t = 0.0;
#pragma unroll
    for (int q = 0; q < 4; q++) t += pox[((size_t)a * 4 + q) * 4096 + px];
    float o = (float)(t + (double)b2[a]);
    float s = (float)(1.0 / (1.0 + exp(-(double)o)));
    scores[idx] = s;
    atomicAdd(&hist[__float_as_uint(s) >> 16], 1u);

    float d[4];
#pragma unroll
    for (int c = 0; c < 4; c++) {
        int oo = 12 + a * 4 + c;
        double u = 0.0;
#pragma unroll
        for (int q = 0; q < 4; q++) u += pox[((size_t)oo * 4 + q) * 4096 + px];
        d[c] = (float)(u + (double)b3[a * 4 + c]);
    }

    int py = px >> 6, pxx = px & 63;
    double cx = pxx * 16.0 + 8.0, cy = py * 16.0 + 8.0;
    int si = a / 3, ri = a - si * 3;
    double scale = (double)(32 << si);
    double ratio = 0.5 * (double)(1 << ri);
    double sq = sqrt(ratio);
    double aw = scale * sq, ah = scale / sq;
    double xc = cx + (double)d[0] * aw;
    double yc = cy + (double)d[1] * ah;
    double wv = aw * exp((double)d[2]);
    double hv = ah * exp((double)d[3]);
    float W = (float)imw[0], H = (float)imh[0];
    float x1 = fminf(fmaxf((float)(xc - wv * 0.5), 0.f), W);
    float x2 = fminf(fmaxf((float)(xc + wv * 0.5), 0.f), W);
    float y1 = fminf(fmaxf((float)(yc - hv * 0.5), 0.f), H);
    float y2 = fminf(fmaxf((float)(yc + hv * 0.5), 0.f), H);
    boxes[(size_t)idx * 4 + 0] = x1;
    boxes[(size_t)idx * 4 + 1] = y1;
    boxes[(size_t)idx * 4 + 2] = x2;
    boxes[(size_t)idx * 4 + 3] = y2;
}

// find boundary bin B1 so that count(bins >= B1) >= 2000, count(bins > B1) < 2000
__global__ __launch_bounds__(256) void k_scanhist(const u32* __restrict__ hist, u32* __restrict__ misc) {
    __shared__ u32 csum[256];
    __shared__ u32 cb[256];
    __shared__ int s_cidx;
    __shared__ u32 s_cacc;
    int t = threadIdx.x;
    u32 sum = 0;
    const uint4* h4 = (const uint4*)(hist + t * 256);
    for (int j = 0; j < 64; j++) { uint4 v = h4[j]; sum += v.x + v.y + v.z + v.w; }
    csum[t] = sum;
    __syncthreads();
    if (t == 0) {
        u32 acc = 0;
        int c = 255;
        for (; c > 0; c--) {
            if (acc + csum[c] >= NKEEP) break;
            acc += csum[c];
        }
        s_cidx = c;
        s_cacc = acc;
    }
    __syncthreads();
    cb[t] = hist[s_cidx * 256 + t];
    __syncthreads();
    if (t == 0) {
        u32 acc = s_cacc;
        int b = 255;
        for (; b > 0; b--) {
            acc += cb[b];
            if (acc >= NKEEP) break;
        }
        misc[1] = (u32)(s_cidx * 256 + b);
    }
}

__global__ __launch_bounds__(256) void k_compact(const float* __restrict__ scores, u32* __restrict__ misc,
                                                 u64* __restrict__ keys) {
    int idx = blockIdx.x * 256 + threadIdx.x;
    if (idx >= A_TOTAL) return;
    u32 bits = __float_as_uint(scores[idx]);
    if ((bits >> 16) >= misc[1]) {
        u32 slot = atomicAdd(&misc[0], 1u);
        if (slot < SORTN) keys[slot] = ((u64)bits << 32) | (u64)(~(u32)idx);
    }
}

// bitonic sort 4096 keys DESC (score desc, index asc), gather cand rows + init suppression words
__global__ __launch_bounds__(1024) void k_sort(const u64* __restrict__ keys, const float* __restrict__ boxes,
                                               float* __restrict__ cand5, u64* __restrict__ suppws) {
    __shared__ u64 lk[SORTN];
    int t = threadIdx.x;
#pragma unroll
    for (int r = 0; r < 4; r++) lk[r * 1024 + t] = keys[r * 1024 + t];
    for (int kk = 2; kk <= SORTN; kk <<= 1) {
        for (int jj = kk >> 1; jj > 0; jj >>= 1) {
            __syncthreads();
#pragma unroll
            for (int rep = 0; rep < 4; rep++) {
                int i = rep * 1024 + t;
                int ixj = i ^ jj;
                if (ixj > i) {
                    u64 a = lk[i], b = lk[ixj];
                    bool sw = ((i & kk) == 0) ? (a < b) : (a > b);
                    if (sw) { lk[i] = b; lk[ixj] = a; }
                }
            }
        }
    }
    __syncthreads();
#pragma unroll
    for (int rep = 0; rep < 2; rep++) {
        int i = rep * 1024 + t;
        bool suppb = true;
        float c0 = 0.f, c1 = 0.f, c2 = 0.f, c3 = 0.f, cs = 0.f;
        if (i < NKEEP) {
            u64 key = lk[i];
            u32 idx = ~(u32)(key & 0xFFFFFFFFull);
            cs = __uint_as_float((u32)(key >> 32));
            c0 = boxes[(size_t)idx * 4 + 0];
            c1 = boxes[(size_t)idx * 4 + 1];
            c2 = boxes[(size_t)idx * 4 + 2];
            c3 = boxes[(size_t)idx * 4 + 3];
            bool valid = ((c2 - c0) >= 16.f) && ((c3 - c1) >= 16.f) && (cs >= 0.05f);
            suppb = !valid;
        }
        cand5[i * 5 + 0] = c0;
        cand5[i * 5 + 1] = c1;
        cand5[i * 5 + 2] = c2;
        cand5[i * 5 + 3] = c3;
        cand5[i * 5 + 4] = cs;
        u64 bal = __ballot(suppb ? 1 : 0);
        if ((t & 63) == 0) suppws[i >> 6] = bal;
    }
}

// IoU > 0.7 bitmask, 64x64 tiles
__global__ __launch_bounds__(64) void k_mask(const float* __restrict__ cand5, u64* __restrict__ mask) {
    __shared__ float cb[64][5];
    int t = threadIdx.x;
    int bi = blockIdx.y, bj = blockIdx.x;
    int j = bj * 64 + t;
    {
        float b0 = cand5[j * 5 + 0], b1v = cand5[j * 5 + 1], b2v = cand5[j * 5 + 2], b3v = cand5[j * 5 + 3];
        cb[t][0] = b0; cb[t][1] = b1v; cb[t][2] = b2v; cb[t][3] = b3v;
        cb[t][4] = (b2v - b0) * (b3v - b1v);
    }
    __syncthreads();
    int i = bi * 64 + t;
    float r0 = cand5[i * 5 + 0], r1 = cand5[i * 5 + 1], r2 = cand5[i * 5 + 2], r3 = cand5[i * 5 + 3];
    float ra = (r2 - r0) * (r3 - r1);
    u64 bits = 0ull;
#pragma unroll 4
    for (int c = 0; c < 64; c++) {
        float lx = fmaxf(r0, cb[c][0]);
        float ly = fmaxf(r1, cb[c][1]);
        float rx = fminf(r2, cb[c][2]);
        float ry = fminf(r3, cb[c][3]);
        float w = fmaxf(rx - lx, 0.f);
        float h = fmaxf(ry - ly, 0.f);
        float inter = w * h;
        float iou = inter / fmaxf(ra + cb[c][4] - inter, 1e-6f);
        if (iou > 0.7f) bits |= (1ull << c);
    }
    mask[(size_t)i * 32 + bj] = bits;
}

// single-wave greedy NMS scan with depth-8 prefetch; writes first <=300 kept rows
__global__ __launch_bounds__(64) void k_scan(const u64* __restrict__ mask, const float* __restrict__ cand5,
                                             const u64* __restrict__ suppws, float* __restrict__ out) {
    int lane = threadIdx.x;
    u64 supp = (lane < 32) ? suppws[lane] : 0ull;
    u64 bufA[8], bufB[8];
    float dA[8], dB[8];
#pragma unroll
    for (int k = 0; k < 8; k++) {
        bufA[k] = (lane < 32) ? mask[(size_t)k * 32 + lane] : 0ull;
        dA[k] = (lane < 5) ? cand5[k * 5 + lane] : 0.f;
    }
    int kcount = 0;
    for (int gq = 0; gq < 256; gq++) {
        int base = gq * 8;
        if (gq < 255) {
            int nb = base + 8;
#pragma unroll
            for (int k = 0; k < 8; k++) {
                bufB[k] = (lane < 32) ? mask[(size_t)(nb + k) * 32 + lane] : 0ull;
                dB[k] = (lane < 5) ? cand5[(nb + k) * 5 + lane] : 0.f;
            }
        }
        int w = gq >> 3;
        u64 cur = __shfl(supp, w);
#pragma unroll
        for (int k = 0; k < 8; k++) {
            int i = base + k;
            if (i < NKEEP && !((cur >> (i & 63)) & 1ull)) {
                if (kcount < NTOPK) {
                    if (lane < 5) out[kcount * 5 + lane] = dA[k];
                    kcount++;
                }
                supp |= bufA[k];
                cur |= __shfl(bufA[k], w);
            }
        }
        if (kcount >= NTOPK) return;
#pragma unroll
        for (int k = 0; k < 8; k++) { bufA[k] = bufB[k]; dA[k] = dB[k]; }
    }
}

extern "C" void kernel_launch(void* const* d_in, const int* in_sizes, int n_in,
                              void* d_out, int out_size, void* d_ws, size_t ws_size,
                              hipStream_t stream) {
    (void)in_sizes; (void)n_in; (void)out_size; (void)ws_size;
    const float* fx = (const float*)d_in[0];
    const float* w1 = (const float*)d_in[1];
    const float* b1 = (const float*)d_in[2];
    const float* w2 = (const float*)d_in[3];
    const float* b2 = (const float*)d_in[4];
    const float* w3 = (const float*)d_in[5];
    const float* b3 = (const float*)d_in[6];
    const int* imh = (const int*)d_in[7];
    const int* imw = (const int*)d_in[8];

    char* ws = (char*)d_ws;
    float*  pacc   = (float*)(ws + OFF_PACC);   // [2][512][4096]; pacc0 becomes x
    double* pox    = (double*)(ws + OFF_POX);
    float*  boxes  = (float*)(ws + OFF_BOXES);
    float*  scores = (float*)(ws + OFF_SCORES);
    u32*    hist   = (u32*)(ws + OFF_HIST);
    u64*    keys   = (u64*)(ws + OFF_KEYS);
    float*  cand5  = (float*)(ws + OFF_CAND5);
    u64*    mask   = (u64*)(ws + OFF_MASK);
    u32*    misc   = (u32*)(ws + OFF_MISC);
    u64*    suppws = (u64*)(ws + OFF_MISC + 64);
    float*  out    = (float*)d_out;

    k_init<<<256, 256, 0, stream>>>(hist, keys, misc, out);
    k_conv1m<<<dim3(32, 8, 2), 512, 0, stream>>>(fx, w1, pacc);
    k_comb<<<8192, 256, 0, stream>>>(pacc, pacc + 2097152, b1);
    k_conv23<<<dim3(64, 4), 256, 0, stream>>>(pacc, w2, w3, pox);
    k_boxes<<<192, 256, 0, stream>>>(pox, b2, b3, imh, imw, boxes, scores, hist);
    k_scanhist<<<1, 256, 0, stream>>>(hist, misc);
    k_compact<<<192, 256, 0, stream>>>(scores, misc, keys);
    k_sort<<<1, 1024, 0, stream>>>(keys, boxes, cand5, suppws);
    k_mask<<<dim3(32, 32), 64, 0, stream>>>(cand5, mask);
    k_scan<<<1, 64, 0, stream>>>(mask, cand5, suppws, out);
}

// Round 9
// 554.818 us; speedup vs baseline: 2.3553x; 1.0107x over previous
//
#include <hip/hip_runtime.h>
#include <math.h>

typedef unsigned int u32;
typedef unsigned long long u64;
typedef unsigned short u16;

typedef float f32x16 __attribute__((ext_vector_type(16)));
typedef short bf16x8 __attribute__((ext_vector_type(8)));

#define A_TOTAL 49152
#define NKEEP 2000
#define NTOPK 300
#define SORTN 4096

// ws layout (bytes)
#define OFF_PACC   0u            // [2][512][4096] f32 = 16,777,216 ; pacc0 becomes x after k_comb
#define OFF_POX    8388608u      // overlays pacc1 (dead after k_comb): 60*4*4096 f64 = 7,864,320
#define OFF_BOXES  16777216u     // 49152*4 f32
#define OFF_SCORES 17563648u     // 49152 f32
#define OFF_HIST   17760256u     // 65536 u32
#define OFF_KEYS   18022400u     // 4096 u64
#define OFF_CAND5  18055168u     // 2048*5 f32
#define OFF_MASK   18096128u     // 2048*32 u64
#define OFF_MISC   18620416u     // [0]=counter,[1]=B1 ; +64B: suppws u64[32]

__global__ __launch_bounds__(256) void k_init(u32* __restrict__ hist, u64* __restrict__ keys,
                                              u32* __restrict__ misc, float* __restrict__ out) {
    int t = blockIdx.x * 256 + threadIdx.x;
    if (t < 65536) hist[t] = 0u;
    if (t < SORTN) keys[t] = 0ull;
    if (t < NTOPK * 5) out[t] = 0.f;
    if (t == 0) misc[0] = 0u;
}

// ---------- bf16 split helpers (all RNE — R7-validated numerics, LOCKED) ----------
__device__ __forceinline__ u16 f2bf(float v) {
    u32 u = __float_as_uint(v);
    return (u16)((u + 0x7FFFu + ((u >> 16) & 1u)) >> 16);
}
__device__ __forceinline__ float bf2f(u16 h) { return __uint_as_float(((u32)h) << 16); }
__device__ __forceinline__ void split3(float v, u16& h, u16& m, u16& l) {
    h = f2bf(v);
    float r1 = v - bf2f(h);
    m = f2bf(r1);
    float r2 = r1 - bf2f(m);
    l = f2bf(r2);
}
__device__ __forceinline__ bf16x8 ldsfrag(const u16* p) {
    const u64* q = (const u64*)p;
    union { u64 w[2]; bf16x8 v; } x;
    x.w[0] = q[0];
    x.w[1] = q[1];
    return x.v;
}

// conv1 via MFMA bf16x3 splits, 6 terms (hh,hm,mh,hl,mm,lh) — R7-validated numerics bitwise.
// Perf fixes vs R7: no min-occupancy bound (no spills); XCD swizzle (bid&7 = co-row -> w1
// slice L2-resident per XCD); W staged as ci-pairs with a-fastest lane order -> packed u32
// LDS writes, conflict-free; fx reg-prefetch depth 2 (covers ~900cyc HBM under MFMA).
// Chunk = 16ci x 9 taps; tile 64co x 128px; K-split x2; LDS 78.4KB -> 2 blocks/CU.
__global__ __launch_bounds__(512) void k_conv1m(const float* __restrict__ fx, const float* __restrict__ w1,
                                                float* __restrict__ pacc) {
    __shared__ u16 sA[3 * 9472];   // 56832 B ; split s at s*9472 u16 ; row = co*148 + tap*16 + ci
    __shared__ u16 sB[3 * 3600];   // 21600 B ; split s at s*3600 u16 ; row = loc*20 + ci
    u32* const sA32 = (u32*)sA;    // split stride 4736 u32
    const int tid = threadIdx.x;
    const int lane = tid & 63;
    const int wid = tid >> 6;       // 0..7
    const int cgw = wid >> 2;       // 0..1 -> co offset 32*cgw
    const int pgw = wid & 3;        // 0..3 -> px group of 32
    const int n = lane & 31;
    const int g = lane >> 5;        // k-octet
    // XCD swizzle: co-row fastest (bid%8 dispatch policy) -> w1 slice L2-local per XCD
    const int bid = blockIdx.x;     // 0..511
    const int yb = bid & 7;
    const int rest = bid >> 3;      // 0..63
    const int bpx = rest & 31;
    const int kh = rest >> 5;       // 0..1
    const int y0 = (bpx >> 2) * 8, x0 = (bpx & 3) * 16;
    const int co0 = yb * 64;
    const int ci_base = kh * 512;

    // ---- W staging: 9 ci-pairs/thread, q = b*8 + a (a fastest) -> packed u32 writes stride-1 ----
    int wgp[9], wlp[9];
#pragma unroll
    for (int j = 0; j < 9; j++) {
        int p = tid + j * 512;          // 0..4607 = 64co x 72 pairs
        int co = p / 72, q = p - co * 72;
        int a = q & 7, b = q >> 3;      // ci pair (2a,2a+1), tap b (0..8)
        wgp[j] = co * 9216 + (2 * a) * 9 + b;   // +9 = second elem (ci+1, same tap)
        wlp[j] = co * 74 + b * 8 + a;           // u32 index in sA32 (consecutive per lane)
    }
    // ---- fx staging: 16ci x 10hy x 18hx = 2880, 6/thread ----
    int fg0[6], fl[6];
#pragma unroll
    for (int j = 0; j < 6; j++) {
        int idx = tid + j * 512;
        bool wr = idx < 2880;
        int ci = idx / 180, rem = idx - ci * 180;
        int hy = rem / 18, hx = rem - hy * 18;
        int gy = y0 + hy - 1, gx = x0 + hx - 1;
        bool ok = wr && gy >= 0 && gy < 64 && gx >= 0 && gx < 64;
        fg0[j] = ok ? (ci * 4096 + gy * 64 + gx) : -1;
        fl[j] = wr ? (rem * 20 + ci) : -1;
    }

    f32x16 acc;
    double accD[16];
#pragma unroll
    for (int i = 0; i < 16; i++) { acc[i] = 0.f; accD[i] = 0.0; }

    float pw[18], pfA[6], pfB[6];
    {   // prologue: W(0), fx(0), fx(1)
        const float* wp = w1 + (size_t)co0 * 9216 + (size_t)ci_base * 9;
#pragma unroll
        for (int j = 0; j < 9; j++) { pw[2 * j] = wp[wgp[j]]; pw[2 * j + 1] = wp[wgp[j] + 9]; }
        const float* f0 = fx + (size_t)ci_base * 4096;
        const float* f1 = fx + (size_t)(ci_base + 16) * 4096;
#pragma unroll
        for (int j = 0; j < 6; j++) {
            pfA[j] = (fg0[j] >= 0) ? f0[fg0[j]] : 0.f;
            pfB[j] = (fg0[j] >= 0) ? f1[fg0[j]] : 0.f;
        }
    }

#pragma unroll 1
    for (int c = 0; c < 32; c++) {
        __syncthreads();            // previous chunk's frag reads done; LDS writable
        // stage W: 3-split RNE, packed u32 pair writes (conflict-free)
#pragma unroll
        for (int j = 0; j < 9; j++) {
            u16 h0, m0, l0, h1, m1, l1;
            split3(pw[2 * j], h0, m0, l0);
            split3(pw[2 * j + 1], h1, m1, l1);
            sA32[wlp[j]] = (u32)h0 | ((u32)h1 << 16);
            sA32[4736 + wlp[j]] = (u32)m0 | ((u32)m1 << 16);
            sA32[9472 + wlp[j]] = (u32)l0 | ((u32)l1 << 16);
        }
        // stage fx: 3-split RNE
#pragma unroll
        for (int j = 0; j < 6; j++) {
            if (fl[j] >= 0) {
                u16 h, m, l;
                split3(pfA[j], h, m, l);
                sB[fl[j]] = h; sB[3600 + fl[j]] = m; sB[7200 + fl[j]] = l;
            }
        }
        __syncthreads();
        // prefetch: W depth 1 (L2-resident after swizzle), fx depth 2
        if (c < 31) {
            const float* wp = w1 + (size_t)co0 * 9216 + (size_t)(ci_base + (c + 1) * 16) * 9;
#pragma unroll
            for (int j = 0; j < 9; j++) { pw[2 * j] = wp[wgp[j]]; pw[2 * j + 1] = wp[wgp[j] + 9]; }
        }
#pragma unroll
        for (int j = 0; j < 6; j++) pfA[j] = pfB[j];
        if (c < 30) {
            const float* fp = fx + (size_t)(ci_base + (c + 2) * 16) * 4096;
#pragma unroll
            for (int j = 0; j < 6; j++) pfB[j] = (fg0[j] >= 0) ? fp[fg0[j]] : 0.f;
        }

        // compute: 9 taps x 6 MFMA (R7 order); drain f32->f64 every 3 taps
#pragma unroll 1
        for (int dy = 0; dy < 3; dy++) {
#pragma unroll
            for (int dx = 0; dx < 3; dx++) {
                const int tap = dy * 3 + dx;
                const int aoff = (cgw * 32 + n) * 148 + tap * 16 + g * 8;
                bf16x8 ah = ldsfrag(&sA[aoff]);
                bf16x8 am = ldsfrag(&sA[9472 + aoff]);
                bf16x8 al = ldsfrag(&sA[18944 + aoff]);
                const int loc = (pgw * 2 + (n >> 4) + dy) * 18 + (n & 15) + dx;
                const int boff = loc * 20 + g * 8;
                bf16x8 bh = ldsfrag(&sB[boff]);
                bf16x8 bm = ldsfrag(&sB[3600 + boff]);
                bf16x8 bl = ldsfrag(&sB[7200 + boff]);
                acc = __builtin_amdgcn_mfma_f32_32x32x16_bf16(ah, bh, acc, 0, 0, 0);
                acc = __builtin_amdgcn_mfma_f32_32x32x16_bf16(ah, bm, acc, 0, 0, 0);
                acc = __builtin_amdgcn_mfma_f32_32x32x16_bf16(am, bh, acc, 0, 0, 0);
                acc = __builtin_amdgcn_mfma_f32_32x32x16_bf16(ah, bl, acc, 0, 0, 0);
                acc = __builtin_amdgcn_mfma_f32_32x32x16_bf16(am, bm, acc, 0, 0, 0);
                acc = __builtin_amdgcn_mfma_f32_32x32x16_bf16(al, bh, acc, 0, 0, 0);
            }
#pragma unroll
            for (int i = 0; i < 16; i++) { accD[i] += (double)acc[i]; acc[i] = 0.f; }
        }
    }

    // epilogue: C/D 32x32 layout: col = n (pixel), row = (rg&3) + 8*(rg>>2) + 4*g (co in group)
    {
        int p = pgw * 32 + n;
        int py = p >> 4, pxx = p & 15;
        int gp = (y0 + py) * 64 + x0 + pxx;
        const int row_hi = 4 * g;
#pragma unroll
        for (int rg = 0; rg < 16; rg++) {
            int co = co0 + cgw * 32 + (rg & 3) + 8 * (rg >> 2) + row_hi;
            pacc[(size_t)kh * 2097152 + (size_t)co * 4096 + gp] = (float)accD[rg];
        }
    }
}

// x = relu(f64(pacc0) + f64(pacc1) + bias), written in place over pacc0
__global__ __launch_bounds__(256) void k_comb(float* __restrict__ x, const float* __restrict__ p1,
                                              const float* __restrict__ b1) {
    int i = blockIdx.x * 256 + threadIdx.x;   // grid 8192 = 2M
    double v = (double)x[i] + (double)p1[i] + (double)b1[i >> 12];
    x[i] = fmaxf((float)v, 0.f);
}

// 1x1 convs, LDS-tiled, ci-quarter partials (f64), bias added later in k_boxes.
__global__ __launch_bounds__(256) void k_conv23(const float* __restrict__ x,
                                                const float* __restrict__ w2, const float* __restrict__ w3,
                                                double* __restrict__ pox) {
    __shared__ float xs[32 * 64];     // [ci][px]
    __shared__ float wsh[60 * 128];   // [o][ci]
    const int tid = threadIdx.x;
    const int px0 = blockIdx.x * 64;
    const int cib = blockIdx.y * 128;
    const int px = tid & 63;
    const int og = tid >> 6;          // 0..3 -> o = og*15 + j

#pragma unroll
    for (int k = 0; k < 30; k++) {
        int e = tid + k * 256;
        int o = e >> 7, ci = e & 127;
        float wv = (o < 12) ? w2[o * 512 + cib + ci] : w3[(size_t)(o - 12) * 512 + cib + ci];
        wsh[o * 128 + ci] = wv;
    }

    double acc[15];
#pragma unroll
    for (int j = 0; j < 15; j++) acc[j] = 0.0;

#pragma unroll 1
    for (int ch = 0; ch < 4; ch++) {
        __syncthreads();
#pragma unroll
        for (int k = 0; k < 8; k++) {
            int e = tid + k * 256;
            int ci = e >> 6, p = e & 63;
            xs[ci * 64 + p] = x[(size_t)(cib + ch * 32 + ci) * 4096 + px0 + p];
        }
        __syncthreads();
#pragma unroll 1
        for (int ci = 0; ci < 32; ci++) {
            double xd = (double)xs[ci * 64 + px];
            const float* wrow = &wsh[ch * 32 + ci];
#pragma unroll
            for (int j = 0; j < 15; j++)
                acc[j] = fma(xd, (double)wrow[(og * 15 + j) * 128], acc[j]);
        }
    }
#pragma unroll
    for (int j = 0; j < 15; j++) {
        int o = og * 15 + j;
        pox[((size_t)o * 4 + blockIdx.y) * 4096 + px0 + px] = acc[j];
    }
}

// decode: combine ci-quarter partials (+bias, round f32), f64 sigmoid/box decode, histogram
__global__ __launch_bounds__(256) void k_boxes(const double* __restrict__ pox,
                                               const float* __restrict__ b2, const float* __restrict__ b3,
                                               const int* __restrict__ imh, const int* __restrict__ imw,
                                               float* __restrict__ boxes, float* __restrict__ scores,
                                               u32* __restrict__ hist) {
    int idx = blockIdx.x * 256 + threadIdx.x;
    if (idx >= A_TOTAL) return;
    int px = idx / 12, a = idx - px * 12;

    double t = 0.0;
#pragma unroll
    for (int q = 0; q < 4; q++) t += pox[((size_t)a * 4 + q) * 4096 + px];
    float o = (float)(t + (double)b2[a]);
    float s = (float)(1.0 / (1.0 + exp(-(double)o)));
    scores[idx] = s;
    atomicAdd(&hist[__float_as_uint(s) >> 16], 1u);

    float d[4];
#pragma unroll
    for (int c = 0; c < 4; c++) {
        int oo = 12 + a * 4 + c;
        double u = 0.0;
#pragma unroll
        for (int q = 0; q < 4; q++) u += pox[((size_t)oo * 4 + q) * 4096 + px];
        d[c] = (float)(u + (double)b3[a * 4 + c]);
    }

    int py = px >> 6, pxx = px & 63;
    double cx = pxx * 16.0 + 8.0, cy = py * 16.0 + 8.0;
    int si = a / 3, ri = a - si * 3;
    double scale = (double)(32 << si);
    double ratio = 0.5 * (double)(1 << ri);
    double sq = sqrt(ratio);
    double aw = scale * sq, ah = scale / sq;
    double xc = cx + (double)d[0] * aw;
    double yc = cy + (double)d[1] * ah;
    double wv = aw * exp((double)d[2]);
    double hv = ah * exp((double)d[3]);
    float W = (float)imw[0], H = (float)imh[0];
    float x1 = fminf(fmaxf((float)(xc - wv * 0.5), 0.f), W);
    float x2 = fminf(fmaxf((float)(xc + wv * 0.5), 0.f), W);
    float y1 = fminf(fmaxf((float)(yc - hv * 0.5), 0.f), H);
    float y2 = fminf(fmaxf((float)(yc + hv * 0.5), 0.f), H);
    boxes[(size_t)idx * 4 + 0] = x1;
    boxes[(size_t)idx * 4 + 1] = y1;
    boxes[(size_t)idx * 4 + 2] = x2;
    boxes[(size_t)idx * 4 + 3] = y2;
}

// find boundary bin B1 so that count(bins >= B1) >= 2000, count(bins > B1) < 2000
__global__ __launch_bounds__(256) void k_scanhist(const u32* __restrict__ hist, u32* __restrict__ misc) {
    __shared__ u32 csum[256];
    __shared__ u32 cb[256];
    __shared__ int s_cidx;
    __shared__ u32 s_cacc;
    int t = threadIdx.x;
    u32 sum = 0;
    const uint4* h4 = (const uint4*)(hist + t * 256);
    for (int j = 0; j < 64; j++) { uint4 v = h4[j]; sum += v.x + v.y + v.z + v.w; }
    csum[t] = sum;
    __syncthreads();
    if (t == 0) {
        u32 acc = 0;
        int c = 255;
        for (; c > 0; c--) {
            if (acc + csum[c] >= NKEEP) break;
            acc += csum[c];
        }
        s_cidx = c;
        s_cacc = acc;
    }
    __syncthreads();
    cb[t] = hist[s_cidx * 256 + t];
    __syncthreads();
    if (t == 0) {
        u32 acc = s_cacc;
        int b = 255;
        for (; b > 0; b--) {
            acc += cb[b];
            if (acc >= NKEEP) break;
        }
        misc[1] = (u32)(s_cidx * 256 + b);
    }
}

__global__ __launch_bounds__(256) void k_compact(const float* __restrict__ scores, u32* __restrict__ misc,
                                                 u64* __restrict__ keys) {
    int idx = blockIdx.x * 256 + threadIdx.x;
    if (idx >= A_TOTAL) return;
    u32 bits = __float_as_uint(scores[idx]);
    if ((bits >> 16) >= misc[1]) {
        u32 slot = atomicAdd(&misc[0], 1u);
        if (slot < SORTN) keys[slot] = ((u64)bits << 32) | (u64)(~(u32)idx);
    }
}

// bitonic sort 4096 keys DESC (score desc, index asc), gather cand rows + init suppression words
__global__ __launch_bounds__(1024) void k_sort(const u64* __restrict__ keys, const float* __restrict__ boxes,
                                               float* __restrict__ cand5, u64* __restrict__ suppws) {
    __shared__ u64 lk[SORTN];
    int t = threadIdx.x;
#pragma unroll
    for (int r = 0; r < 4; r++) lk[r * 1024 + t] = keys[r * 1024 + t];
    for (int kk = 2; kk <= SORTN; kk <<= 1) {
        for (int jj = kk >> 1; jj > 0; jj >>= 1) {
            __syncthreads();
#pragma unroll
            for (int rep = 0; rep < 4; rep++) {
                int i = rep * 1024 + t;
                int ixj = i ^ jj;
                if (ixj > i) {
                    u64 a = lk[i], b = lk[ixj];
                    bool sw = ((i & kk) == 0) ? (a < b) : (a > b);
                    if (sw) { lk[i] = b; lk[ixj] = a; }
                }
            }
        }
    }
    __syncthreads();
#pragma unroll
    for (int rep = 0; rep < 2; rep++) {
        int i = rep * 1024 + t;
        bool suppb = true;
        float c0 = 0.f, c1 = 0.f, c2 = 0.f, c3 = 0.f, cs = 0.f;
        if (i < NKEEP) {
            u64 key = lk[i];
            u32 idx = ~(u32)(key & 0xFFFFFFFFull);
            cs = __uint_as_float((u32)(key >> 32));
            c0 = boxes[(size_t)idx * 4 + 0];
            c1 = boxes[(size_t)idx * 4 + 1];
            c2 = boxes[(size_t)idx * 4 + 2];
            c3 = boxes[(size_t)idx * 4 + 3];
            bool valid = ((c2 - c0) >= 16.f) && ((c3 - c1) >= 16.f) && (cs >= 0.05f);
            suppb = !valid;
        }
        cand5[i * 5 + 0] = c0;
        cand5[i * 5 + 1] = c1;
        cand5[i * 5 + 2] = c2;
        cand5[i * 5 + 3] = c3;
        cand5[i * 5 + 4] = cs;
        u64 bal = __ballot(suppb ? 1 : 0);
        if ((t & 63) == 0) suppws[i >> 6] = bal;
    }
}

// IoU > 0.7 bitmask, 64x64 tiles
__global__ __launch_bounds__(64) void k_mask(const float* __restrict__ cand5, u64* __restrict__ mask) {
    __shared__ float cb[64][5];
    int t = threadIdx.x;
    int bi = blockIdx.y, bj = blockIdx.x;
    int j = bj * 64 + t;
    {
        float b0 = cand5[j * 5 + 0], b1v = cand5[j * 5 + 1], b2v = cand5[j * 5 + 2], b3v = cand5[j * 5 + 3];
        cb[t][0] = b0; cb[t][1] = b1v; cb[t][2] = b2v; cb[t][3] = b3v;
        cb[t][4] = (b2v - b0) * (b3v - b1v);
    }
    __syncthreads();
    int i = bi * 64 + t;
    float r0 = cand5[i * 5 + 0], r1 = cand5[i * 5 + 1], r2 = cand5[i * 5 + 2], r3 = cand5[i * 5 + 3];
    float ra = (r2 - r0) * (r3 - r1);
    u64 bits = 0ull;
#pragma unroll 4
    for (int c = 0; c < 64; c++) {
        float lx = fmaxf(r0, cb[c][0]);
        float ly = fmaxf(r1, cb[c][1]);
        float rx = fminf(r2, cb[c][2]);
        float ry = fminf(r3, cb[c][3]);
        float w = fmaxf(rx - lx, 0.f);
        float h = fmaxf(ry - ly, 0.f);
        float inter = w * h;
        float iou = inter / fmaxf(ra + cb[c][4] - inter, 1e-6f);
        if (iou > 0.7f) bits |= (1ull << c);
    }
    mask[(size_t)i * 32 + bj] = bits;
}

// single-wave greedy NMS scan with depth-8 prefetch; writes first <=300 kept rows
__global__ __launch_bounds__(64) void k_scan(const u64* __restrict__ mask, const float* __restrict__ cand5,
                                             const u64* __restrict__ suppws, float* __restrict__ out) {
    int lane = threadIdx.x;
    u64 supp = (lane < 32) ? suppws[lane] : 0ull;
    u64 bufA[8], bufB[8];
    float dA[8], dB[8];
#pragma unroll
    for (int k = 0; k < 8; k++) {
        bufA[k] = (lane < 32) ? mask[(size_t)k * 32 + lane] : 0ull;
        dA[k] = (lane < 5) ? cand5[k * 5 + lane] : 0.f;
    }
    int kcount = 0;
    for (int gq = 0; gq < 256; gq++) {
        int base = gq * 8;
        if (gq < 255) {
            int nb = base + 8;
#pragma unroll
            for (int k = 0; k < 8; k++) {
                bufB[k] = (lane < 32) ? mask[(size_t)(nb + k) * 32 + lane] : 0ull;
                dB[k] = (lane < 5) ? cand5[(nb + k) * 5 + lane] : 0.f;
            }
        }
        int w = gq >> 3;
        u64 cur = __shfl(supp, w);
#pragma unroll
        for (int k = 0; k < 8; k++) {
            int i = base + k;
            if (i < NKEEP && !((cur >> (i & 63)) & 1ull)) {
                if (kcount < NTOPK) {
                    if (lane < 5) out[kcount * 5 + lane] = dA[k];
                    kcount++;
                }
                supp |= bufA[k];
                cur |= __shfl(bufA[k], w);
            }
        }
        if (kcount >= NTOPK) return;
#pragma unroll
        for (int k = 0; k < 8; k++) { bufA[k] = bufB[k]; dA[k] = dB[k]; }
    }
}

extern "C" void kernel_launch(void* const* d_in, const int* in_sizes, int n_in,
                              void* d_out, int out_size, void* d_ws, size_t ws_size,
                              hipStream_t stream) {
    (void)in_sizes; (void)n_in; (void)out_size; (void)ws_size;
    const float* fx = (const float*)d_in[0];
    const float* w1 = (const float*)d_in[1];
    const float* b1 = (const float*)d_in[2];
    const float* w2 = (const float*)d_in[3];
    const float* b2 = (const float*)d_in[4];
    const float* w3 = (const float*)d_in[5];
    const float* b3 = (const float*)d_in[6];
    const int* imh = (const int*)d_in[7];
    const int* imw = (const int*)d_in[8];

    char* ws = (char*)d_ws;
    float*  pacc   = (float*)(ws + OFF_PACC);   // [2][512][4096]; pacc0 becomes x
    double* pox    = (double*)(ws + OFF_POX);
    float*  boxes  = (float*)(ws + OFF_BOXES);
    float*  scores = (float*)(ws + OFF_SCORES);
    u32*    hist   = (u32*)(ws + OFF_HIST);
    u64*    keys   = (u64*)(ws + OFF_KEYS);
    float*  cand5  = (float*)(ws + OFF_CAND5);
    u64*    mask   = (u64*)(ws + OFF_MASK);
    u32*    misc   = (u32*)(ws + OFF_MISC);
    u64*    suppws = (u64*)(ws + OFF_MISC + 64);
    float*  out    = (float*)d_out;

    k_init<<<256, 256, 0, stream>>>(hist, keys, misc, out);
    k_conv1m<<<512, 512, 0, stream>>>(fx, w1, pacc);
    k_comb<<<8192, 256, 0, stream>>>(pacc, pacc + 2097152, b1);
    k_conv23<<<dim3(64, 4), 256, 0, stream>>>(pacc, w2, w3, pox);
    k_boxes<<<192, 256, 0, stream>>>(pox, b2, b3, imh, imw, boxes, scores, hist);
    k_scanhist<<<1, 256, 0, stream>>>(hist, misc);
    k_compact<<<192, 256, 0, stream>>>(scores, misc, keys);
    k_sort<<<1, 1024, 0, stream>>>(keys, boxes, cand5, suppws);
    k_mask<<<dim3(32, 32), 64, 0, stream>>>(cand5, mask);
    k_scan<<<1, 64, 0, stream>>>(mask, cand5, suppws, out);
}

// Round 11
// 481.418 us; speedup vs baseline: 2.7144x; 1.1525x over previous
//
#include <hip/hip_runtime.h>
#include <math.h>

typedef unsigned int u32;
typedef unsigned long long u64;
typedef unsigned short u16;

typedef float f32x16 __attribute__((ext_vector_type(16)));
typedef short bf16x8 __attribute__((ext_vector_type(8)));

#define A_TOTAL 49152
#define NKEEP 2000
#define NTOPK 300
#define SORTN 4096

// ws layout (bytes)
#define OFF_PACC   0u            // [2][512][4096] f32 = 16,777,216 ; pacc0 becomes x after k_comb
#define OFF_POX    8388608u      // overlays pacc1 (dead after k_comb): 60*4*4096 f64 = 7,864,320
#define OFF_BOXES  16777216u     // 49152*4 f32
#define OFF_SCORES 17563648u     // 49152 f32
#define OFF_HIST   17760256u     // 65536 u32
#define OFF_KEYS   18022400u     // 4096 u64
#define OFF_CAND5  18055168u     // 2048*5 f32
#define OFF_MASK   18096128u     // 2048*32 u64
#define OFF_MISC   18620416u     // [0]=counter,[1]=B1 ; +64B: suppws u64[32]
#define OFF_PREW   18624512u     // [2kh][8yb][32c][3s][1152 units x 16B] = 28,311,552
#define WS_NEED    46936064ull

__global__ __launch_bounds__(256) void k_init(u32* __restrict__ hist, u64* __restrict__ keys,
                                              u32* __restrict__ misc, float* __restrict__ out) {
    int t = blockIdx.x * 256 + threadIdx.x;
    if (t < 65536) hist[t] = 0u;
    if (t < SORTN) keys[t] = 0ull;
    if (t < NTOPK * 5) out[t] = 0.f;
    if (t == 0) misc[0] = 0u;
}

// ---------- bf16 split helpers (all RNE — R7/R9-validated numerics, LOCKED) ----------
__device__ __forceinline__ u16 f2bf(float v) {
    u32 u = __float_as_uint(v);
    return (u16)((u + 0x7FFFu + ((u >> 16) & 1u)) >> 16);
}
__device__ __forceinline__ float bf2f(u16 h) { return __uint_as_float(((u32)h) << 16); }
__device__ __forceinline__ void split3(float v, u16& h, u16& m, u16& l) {
    h = f2bf(v);
    float r1 = v - bf2f(h);
    m = f2bf(r1);
    float r2 = r1 - bf2f(m);
    l = f2bf(r2);
}
__device__ __forceinline__ bf16x8 ldsfrag(const u16* p) {
    const u64* q = (const u64*)p;
    union { u64 w[2]; bf16x8 v; } x;
    x.w[0] = q[0];
    x.w[1] = q[1];
    return x.v;
}
__device__ __forceinline__ void gll16(const void* g, void* l) {
    __builtin_amdgcn_global_load_lds((const __attribute__((address_space(1))) void*)g,
                                     (__attribute__((address_space(3))) void*)l, 16, 0, 0);
}
__device__ __forceinline__ void gll4(const void* g, void* l) {
    __builtin_amdgcn_global_load_lds((const __attribute__((address_space(1))) void*)g,
                                     (__attribute__((address_space(3))) void*)l, 4, 0, 0);
}

// Pre-split w1 into bf16 h/m/l triples, laid out EXACTLY in conv1m's per-(kh,yb,c) LDS
// staging order: unit (tap,g,co) = 16B = 8 bf16 (ci octet g*8..g*8+7 at that tap).
// preW[(((kh*8+yb)*32+c)*3+s)*1152 + (tap*2+g)*64 + co]  (uint4 units)
// Decode space = 64co x 2g x 9tap x 32c x 8yb x 2kh = 589,824 threads -> grid 2304x256.
// (R10 BUG: grid was 1152 -> kh=1 half of preW never written, read 0xAA poison.)
__global__ __launch_bounds__(256) void k_splitw(const float* __restrict__ w1, uint4* __restrict__ preW) {
    int u = blockIdx.x * 256 + threadIdx.x;     // 0..589823
    int co = u & 63;
    int r1 = u >> 6;
    int g = r1 & 1;
    int r2 = r1 >> 1;
    int tap = r2 % 9;
    int r3 = r2 / 9;
    int c = r3 & 31;
    int r4 = r3 >> 5;
    int yb = r4 & 7;
    int kh = r4 >> 3;
    int ci0 = kh * 512 + c * 16 + g * 8;
    const float* wp = w1 + (size_t)(yb * 64 + co) * 9216 + (size_t)ci0 * 9 + tap;
    union { u16 q[8]; uint4 v; } H, M, L;
#pragma unroll
    for (int i = 0; i < 8; i++) {
        u16 h, m, l;
        split3(wp[i * 9], h, m, l);
        H.q[i] = h; M.q[i] = m; L.q[i] = l;
    }
    size_t base = (size_t)(((kh * 8 + yb) * 32 + c) * 3) * 1152 + (size_t)((tap * 2 + g) * 64 + co);
    preW[base] = H.v;
    preW[base + 1152] = M.v;
    preW[base + 2304] = L.v;
}

// conv1 via MFMA bf16x3 splits, 6 terms — numerics bitwise-identical to R9 (same bf16
// triples, same MFMA order, same drains). W staging = 9 global_load_lds from preW
// (zero VALU / zero ds_write); A-LDS linear [s][(tap*2+g)*64+co][16B] -> contiguous
// 16B/lane reads, conflict-free. fx staging packed to u32 ci-pairs (9 writes vs 18).
__global__ __launch_bounds__(512) void k_conv1m(const float* __restrict__ fx, const uint4* __restrict__ preW,
                                                float* __restrict__ pacc) {
    __shared__ __align__(16) u16 sA[3 * 9216];   // 55296 B ; split s at s*9216 u16
    __shared__ __align__(16) u16 sB[3 * 3600];   // 21600 B ; split s at s*3600 u16 ; row = loc*20 + ci
    u32* const sB32 = (u32*)sB;                  // split stride 1800 u32, row 10 u32
    const int tid = threadIdx.x;
    const int lane = tid & 63;
    const int wid = tid >> 6;       // 0..7
    const int cgw = wid >> 2;       // 0..1 -> co offset 32*cgw
    const int pgw = wid & 3;        // 0..3 -> px group of 32
    const int n = lane & 31;
    const int g = lane >> 5;        // k-octet
    const int bid = blockIdx.x;     // 0..511 ; bid&7 = co-row -> XCD-local w slice
    const int yb = bid & 7;
    const int rest = bid >> 3;
    const int bpx = rest & 31;
    const int kh = rest >> 5;
    const int y0 = (bpx >> 2) * 8, x0 = (bpx & 3) * 16;
    const int ci_base = kh * 512;

    // ---- fx staging: 180 loc x 8 ci-pairs = 1440 items, 3/thread, u32-packed writes ----
    int fgp[3], flp[3];
    bool wrp[3], ldp[3];
#pragma unroll
    for (int j = 0; j < 3; j++) {
        int p = tid + j * 512;
        bool wr = p < 1440;
        int a = p / 180, rem = p - a * 180;         // rem fastest -> coalesced gpos
        int hy = rem / 18, hx = rem - hy * 18;
        int gy = y0 + hy - 1, gx = x0 + hx - 1;
        bool ok = wr && gy >= 0 && gy < 64 && gx >= 0 && gx < 64;
        wrp[j] = wr;
        ldp[j] = ok;
        fgp[j] = ok ? ((2 * a) * 4096 + gy * 64 + gx) : 0;
        flp[j] = wr ? (rem * 10 + a) : 0;
    }

    f32x16 acc;
    double accD[16];
#pragma unroll
    for (int i = 0; i < 16; i++) { acc[i] = 0.f; accD[i] = 0.0; }

    float pA0[3], pA1[3], pB0[3], pB1[3];
    {   // prologue: fx(0), fx(1)
        const float* f0 = fx + (size_t)ci_base * 4096;
        const float* f1 = fx + (size_t)(ci_base + 16) * 4096;
#pragma unroll
        for (int j = 0; j < 3; j++) {
            pA0[j] = ldp[j] ? f0[fgp[j]] : 0.f;
            pA1[j] = ldp[j] ? f0[fgp[j] + 4096] : 0.f;
            pB0[j] = ldp[j] ? f1[fgp[j]] : 0.f;
            pB1[j] = ldp[j] ? f1[fgp[j] + 4096] : 0.f;
        }
    }
    const char* wbase = (const char*)preW + (size_t)((kh * 8 + yb) * 32) * 3 * 18432;
    char* const sAc = (char*)sA;

#pragma unroll 1
    for (int c = 0; c < 32; c++) {
        __syncthreads();            // previous chunk's frag reads done; LDS writable
        // W staging: direct global->LDS DMA (L2-resident slice)
        const char* wsrc = wbase + (size_t)c * 3 * 18432;
#pragma unroll
        for (int s = 0; s < 3; s++) {
            gll16(wsrc + s * 18432 + tid * 16,         sAc + s * 18432 + wid * 1024);
            gll16(wsrc + s * 18432 + 8192 + tid * 16,  sAc + s * 18432 + 8192 + wid * 1024);
            gll4 (wsrc + s * 18432 + 16384 + tid * 4,  sAc + s * 18432 + 16384 + wid * 256);
        }
        // fx staging: 3-split RNE, packed u32 pair writes
#pragma unroll
        for (int j = 0; j < 3; j++) {
            if (wrp[j]) {
                u16 h0, m0, l0, h1, m1, l1;
                split3(pA0[j], h0, m0, l0);
                split3(pA1[j], h1, m1, l1);
                sB32[flp[j]] = (u32)h0 | ((u32)h1 << 16);
                sB32[1800 + flp[j]] = (u32)m0 | ((u32)m1 << 16);
                sB32[3600 + flp[j]] = (u32)l0 | ((u32)l1 << 16);
            }
        }
        __syncthreads();
        // fx prefetch depth 2 (lands under MFMA compute)
#pragma unroll
        for (int j = 0; j < 3; j++) { pA0[j] = pB0[j]; pA1[j] = pB1[j]; }
        if (c < 30) {
            const float* fp = fx + (size_t)(ci_base + (c + 2) * 16) * 4096;
#pragma unroll
            for (int j = 0; j < 3; j++) {
                pB0[j] = ldp[j] ? fp[fgp[j]] : 0.f;
                pB1[j] = ldp[j] ? fp[fgp[j] + 4096] : 0.f;
            }
        }

        // compute: 9 taps x 6 MFMA (R7/R9 order); drain f32->f64 every 3 taps
#pragma unroll 1
        for (int dy = 0; dy < 3; dy++) {
#pragma unroll
            for (int dx = 0; dx < 3; dx++) {
                const int tap = dy * 3 + dx;
                const int aoff = ((tap * 2 + g) * 64 + cgw * 32 + n) * 8;
                bf16x8 ah = ldsfrag(&sA[aoff]);
                bf16x8 am = ldsfrag(&sA[9216 + aoff]);
                bf16x8 al = ldsfrag(&sA[18432 + aoff]);
                const int loc = (pgw * 2 + (n >> 4) + dy) * 18 + (n & 15) + dx;
                const int boff = loc * 20 + g * 8;
                bf16x8 bh = ldsfrag(&sB[boff]);
                bf16x8 bm = ldsfrag(&sB[3600 + boff]);
                bf16x8 bl = ldsfrag(&sB[7200 + boff]);
                acc = __builtin_amdgcn_mfma_f32_32x32x16_bf16(ah, bh, acc, 0, 0, 0);
                acc = __builtin_amdgcn_mfma_f32_32x32x16_bf16(ah, bm, acc, 0, 0, 0);
                acc = __builtin_amdgcn_mfma_f32_32x32x16_bf16(am, bh, acc, 0, 0, 0);
                acc = __builtin_amdgcn_mfma_f32_32x32x16_bf16(ah, bl, acc, 0, 0, 0);
                acc = __builtin_amdgcn_mfma_f32_32x32x16_bf16(am, bm, acc, 0, 0, 0);
                acc = __builtin_amdgcn_mfma_f32_32x32x16_bf16(al, bh, acc, 0, 0, 0);
            }
#pragma unroll
            for (int i = 0; i < 16; i++) { accD[i] += (double)acc[i]; acc[i] = 0.f; }
        }
    }

    // epilogue: C/D 32x32 layout: col = n (pixel), row = (rg&3) + 8*(rg>>2) + 4*g
    {
        int p = pgw * 32 + n;
        int py = p >> 4, pxx = p & 15;
        int gp = (y0 + py) * 64 + x0 + pxx;
        const int row_hi = 4 * g;
#pragma unroll
        for (int rg = 0; rg < 16; rg++) {
            int co = yb * 64 + cgw * 32 + (rg & 3) + 8 * (rg >> 2) + row_hi;
            pacc[(size_t)kh * 2097152 + (size_t)co * 4096 + gp] = (float)accD[rg];
        }
    }
}

// Fallback (ws too small for preW): R9 kernel verbatim — runtime W split + u32-packed writes.
__global__ __launch_bounds__(512) void k_conv1m_fb(const float* __restrict__ fx, const float* __restrict__ w1,
                                                   float* __restrict__ pacc) {
    __shared__ u16 sA[3 * 9472];
    __shared__ u16 sB[3 * 3600];
    u32* const sA32 = (u32*)sA;
    const int tid = threadIdx.x;
    const int lane = tid & 63;
    const int wid = tid >> 6;
    const int cgw = wid >> 2;
    const int pgw = wid & 3;
    const int n = lane & 31;
    const int g = lane >> 5;
    const int bid = blockIdx.x;
    const int yb = bid & 7;
    const int rest = bid >> 3;
    const int bpx = rest & 31;
    const int kh = rest >> 5;
    const int y0 = (bpx >> 2) * 8, x0 = (bpx & 3) * 16;
    const int co0 = yb * 64;
    const int ci_base = kh * 512;

    int wgp[9], wlp[9];
#pragma unroll
    for (int j = 0; j < 9; j++) {
        int p = tid + j * 512;
        int co = p / 72, q = p - co * 72;
        int a = q & 7, b = q >> 3;
        wgp[j] = co * 9216 + (2 * a) * 9 + b;
        wlp[j] = co * 74 + b * 8 + a;
    }
    int fg0[6], fl[6];
#pragma unroll
    for (int j = 0; j < 6; j++) {
        int idx = tid + j * 512;
        bool wr = idx < 2880;
        int ci = idx / 180, rem = idx - ci * 180;
        int hy = rem / 18, hx = rem - hy * 18;
        int gy = y0 + hy - 1, gx = x0 + hx - 1;
        bool ok = wr && gy >= 0 && gy < 64 && gx >= 0 && gx < 64;
        fg0[j] = ok ? (ci * 4096 + gy * 64 + gx) : -1;
        fl[j] = wr ? (rem * 20 + ci) : -1;
    }

    f32x16 acc;
    double accD[16];
#pragma unroll
    for (int i = 0; i < 16; i++) { acc[i] = 0.f; accD[i] = 0.0; }

    float pw[18], pfA[6], pfB[6];
    {
        const float* wp = w1 + (size_t)co0 * 9216 + (size_t)ci_base * 9;
#pragma unroll
        for (int j = 0; j < 9; j++) { pw[2 * j] = wp[wgp[j]]; pw[2 * j + 1] = wp[wgp[j] + 9]; }
        const float* f0 = fx + (size_t)ci_base * 4096;
        const float* f1 = fx + (size_t)(ci_base + 16) * 4096;
#pragma unroll
        for (int j = 0; j < 6; j++) {
            pfA[j] = (fg0[j] >= 0) ? f0[fg0[j]] : 0.f;
            pfB[j] = (fg0[j] >= 0) ? f1[fg0[j]] : 0.f;
        }
    }

#pragma unroll 1
    for (int c = 0; c < 32; c++) {
        __syncthreads();
#pragma unroll
        for (int j = 0; j < 9; j++) {
            u16 h0, m0, l0, h1, m1, l1;
            split3(pw[2 * j], h0, m0, l0);
            split3(pw[2 * j + 1], h1, m1, l1);
            sA32[wlp[j]] = (u32)h0 | ((u32)h1 << 16);
            sA32[4736 + wlp[j]] = (u32)m0 | ((u32)m1 << 16);
            sA32[9472 + wlp[j]] = (u32)l0 | ((u32)l1 << 16);
        }
#pragma unroll
        for (int j = 0; j < 6; j++) {
            if (fl[j] >= 0) {
                u16 h, m, l;
                split3(pfA[j], h, m, l);
                sB[fl[j]] = h; sB[3600 + fl[j]] = m; sB[7200 + fl[j]] = l;
            }
        }
        __syncthreads();
        if (c < 31) {
            const float* wp = w1 + (size_t)co0 * 9216 + (size_t)(ci_base + (c + 1) * 16) * 9;
#pragma unroll
            for (int j = 0; j < 9; j++) { pw[2 * j] = wp[wgp[j]]; pw[2 * j + 1] = wp[wgp[j] + 9]; }
        }
#pragma unroll
        for (int j = 0; j < 6; j++) pfA[j] = pfB[j];
        if (c < 30) {
            const float* fp = fx + (size_t)(ci_base + (c + 2) * 16) * 4096;
#pragma unroll
            for (int j = 0; j < 6; j++) pfB[j] = (fg0[j] >= 0) ? fp[fg0[j]] : 0.f;
        }

#pragma unroll 1
        for (int dy = 0; dy < 3; dy++) {
#pragma unroll
            for (int dx = 0; dx < 3; dx++) {
                const int tap = dy * 3 + dx;
                const int aoff = (cgw * 32 + n) * 148 + tap * 16 + g * 8;
                bf16x8 ah = ldsfrag(&sA[aoff]);
                bf16x8 am = ldsfrag(&sA[9472 + aoff]);
                bf16x8 al = ldsfrag(&sA[18944 + aoff]);
                const int loc = (pgw * 2 + (n >> 4) + dy) * 18 + (n & 15) + dx;
                const int boff = loc * 20 + g * 8;
                bf16x8 bh = ldsfrag(&sB[boff]);
                bf16x8 bm = ldsfrag(&sB[3600 + boff]);
                bf16x8 bl = ldsfrag(&sB[7200 + boff]);
                acc = __builtin_amdgcn_mfma_f32_32x32x16_bf16(ah, bh, acc, 0, 0, 0);
                acc = __builtin_amdgcn_mfma_f32_32x32x16_bf16(ah, bm, acc, 0, 0, 0);
                acc = __builtin_amdgcn_mfma_f32_32x32x16_bf16(am, bh, acc, 0, 0, 0);
                acc = __builtin_amdgcn_mfma_f32_32x32x16_bf16(ah, bl, acc, 0, 0, 0);
                acc = __builtin_amdgcn_mfma_f32_32x32x16_bf16(am, bm, acc, 0, 0, 0);
                acc = __builtin_amdgcn_mfma_f32_32x32x16_bf16(al, bh, acc, 0, 0, 0);
            }
#pragma unroll
            for (int i = 0; i < 16; i++) { accD[i] += (double)acc[i]; acc[i] = 0.f; }
        }
    }

    {
        int p = pgw * 32 + n;
        int py = p >> 4, pxx = p & 15;
        int gp = (y0 + py) * 64 + x0 + pxx;
        const int row_hi = 4 * g;
#pragma unroll
        for (int rg = 0; rg < 16; rg++) {
            int co = co0 + cgw * 32 + (rg & 3) + 8 * (rg >> 2) + row_hi;
            pacc[(size_t)kh * 2097152 + (size_t)co * 4096 + gp] = (float)accD[rg];
        }
    }
}

// x = relu(f64(pacc0) + f64(pacc1) + bias), written in place over pacc0
__global__ __launch_bounds__(256) void k_comb(float* __restrict__ x, const float* __restrict__ p1,
                                              const float* __restrict__ b1) {
    int i = blockIdx.x * 256 + threadIdx.x;
    double v = (double)x[i] + (double)p1[i] + (double)b1[i >> 12];
    x[i] = fmaxf((float)v, 0.f);
}

// 1x1 convs, LDS-tiled, ci-quarter partials (f64), bias added later in k_boxes.
__global__ __launch_bounds__(256) void k_conv23(const float* __restrict__ x,
                                                const float* __restrict__ w2, const float* __restrict__ w3,
                                                double* __restrict__ pox) {
    __shared__ float xs[32 * 64];
    __shared__ float wsh[60 * 128];
    const int tid = threadIdx.x;
    const int px0 = blockIdx.x * 64;
    const int cib = blockIdx.y * 128;
    const int px = tid & 63;
    const int og = tid >> 6;

#pragma unroll
    for (int k = 0; k < 30; k++) {
        int e = tid + k * 256;
        int o = e >> 7, ci = e & 127;
        float wv = (o < 12) ? w2[o * 512 + cib + ci] : w3[(size_t)(o - 12) * 512 + cib + ci];
        wsh[o * 128 + ci] = wv;
    }

    double acc[15];
#pragma unroll
    for (int j = 0; j < 15; j++) acc[j] = 0.0;

#pragma unroll 1
    for (int ch = 0; ch < 4; ch++) {
        __syncthreads();
#pragma unroll
        for (int k = 0; k < 8; k++) {
            int e = tid + k * 256;
            int ci = e >> 6, p = e & 63;
            xs[ci * 64 + p] = x[(size_t)(cib + ch * 32 + ci) * 4096 + px0 + p];
        }
        __syncthreads();
#pragma unroll 1
        for (int ci = 0; ci < 32; ci++) {
            double xd = (double)xs[ci * 64 + px];
            const float* wrow = &wsh[ch * 32 + ci];
#pragma unroll
            for (int j = 0; j < 15; j++)
                acc[j] = fma(xd, (double)wrow[(og * 15 + j) * 128], acc[j]);
        }
    }
#pragma unroll
    for (int j = 0; j < 15; j++) {
        int o = og * 15 + j;
        pox[((size_t)o * 4 + blockIdx.y) * 4096 + px0 + px] = acc[j];
    }
}

// decode: combine ci-quarter partials (+bias, round f32), f64 sigmoid/box decode, histogram
__global__ __launch_bounds__(256) void k_boxes(const double* __restrict__ pox,
                                               const float* __restrict__ b2, const float* __restrict__ b3,
                                               const int* __restrict__ imh, const int* __restrict__ imw,
                                               float* __restrict__ boxes, float* __restrict__ scores,
                                               u32* __restrict__ hist) {
    int idx = blockIdx.x * 256 + threadIdx.x;
    if (idx >= A_TOTAL) return;
    int px = idx / 12, a = idx - px * 12;

    double t = 0.0;
#pragma unroll
    for (int q = 0; q < 4; q++) t += pox[((size_t)a * 4 + q) * 4096 + px];
    float o = (float)(t + (double)b2[a]);
    float s = (float)(1.0 / (1.0 + exp(-(double)o)));
    scores[idx] = s;
    atomicAdd(&hist[__float_as_uint(s) >> 16], 1u);

    float d[4];
#pragma unroll
    for (int c = 0; c < 4; c++) {
        int oo = 12 + a * 4 + c;
        double u = 0.0;
#pragma unroll
        for (int q = 0; q < 4; q++) u += pox[((size_t)oo * 4 + q) * 4096 + px];
        d[c] = (float)(u + (double)b3[a * 4 + c]);
    }

    int py = px >> 6, pxx = px & 63;
    double cx = pxx * 16.0 + 8.0, cy = py * 16.0 + 8.0;
    int si = a / 3, ri = a - si * 3;
    double scale = (double)(32 << si);
    double ratio = 0.5 * (double)(1 << ri);
    double sq = sqrt(ratio);
    double aw = scale * sq, ah = scale / sq;
    double xc = cx + (double)d[0] * aw;
    double yc = cy + (double)d[1] * ah;
    double wv = aw * exp((double)d[2]);
    double hv = ah * exp((double)d[3]);
    float W = (float)imw[0], H = (float)imh[0];
    float x1 = fminf(fmaxf((float)(xc - wv * 0.5), 0.f), W);
    float x2 = fminf(fmaxf((float)(xc + wv * 0.5), 0.f), W);
    float y1 = fminf(fmaxf((float)(yc - hv * 0.5), 0.f), H);
    float y2 = fminf(fmaxf((float)(yc + hv * 0.5), 0.f), H);
    boxes[(size_t)idx * 4 + 0] = x1;
    boxes[(size_t)idx * 4 + 1] = y1;
    boxes[(size_t)idx * 4 + 2] = x2;
    boxes[(size_t)idx * 4 + 3] = y2;
}

// find boundary bin B1 so that count(bins >= B1) >= 2000, count(bins > B1) < 2000
__global__ __launch_bounds__(256) void k_scanhist(const u32* __restrict__ hist, u32* __restrict__ misc) {
    __shared__ u32 csum[256];
    __shared__ u32 cb[256];
    __shared__ int s_cidx;
    __shared__ u32 s_cacc;
    int t = threadIdx.x;
    u32 sum = 0;
    const uint4* h4 = (const uint4*)(hist + t * 256);
    for (int j = 0; j < 64; j++) { uint4 v = h4[j]; sum += v.x + v.y + v.z + v.w; }
    csum[t] = sum;
    __syncthreads();
    if (t == 0) {
        u32 acc = 0;
        int c = 255;
        for (; c > 0; c--) {
            if (acc + csum[c] >= NKEEP) break;
            acc += csum[c];
        }
        s_cidx = c;
        s_cacc = acc;
    }
    __syncthreads();
    cb[t] = hist[s_cidx * 256 + t];
    __syncthreads();
    if (t == 0) {
        u32 acc = s_cacc;
        int b = 255;
        for (; b > 0; b--) {
            acc += cb[b];
            if (acc >= NKEEP) break;
        }
        misc[1] = (u32)(s_cidx * 256 + b);
    }
}

__global__ __launch_bounds__(256) void k_compact(const float* __restrict__ scores, u32* __restrict__ misc,
                                                 u64* __restrict__ keys) {
    int idx = blockIdx.x * 256 + threadIdx.x;
    if (idx >= A_TOTAL) return;
    u32 bits = __float_as_uint(scores[idx]);
    if ((bits >> 16) >= misc[1]) {
        u32 slot = atomicAdd(&misc[0], 1u);
        if (slot < SORTN) keys[slot] = ((u64)bits << 32) | (u64)(~(u32)idx);
    }
}

// bitonic sort 4096 keys DESC (score desc, index asc), gather cand rows + init suppression words
__global__ __launch_bounds__(1024) void k_sort(const u64* __restrict__ keys, const float* __restrict__ boxes,
                                               float* __restrict__ cand5, u64* __restrict__ suppws) {
    __shared__ u64 lk[SORTN];
    int t = threadIdx.x;
#pragma unroll
    for (int r = 0; r < 4; r++) lk[r * 1024 + t] = keys[r * 1024 + t];
    for (int kk = 2; kk <= SORTN; kk <<= 1) {
        for (int jj = kk >> 1; jj > 0; jj >>= 1) {
            __syncthreads();
#pragma unroll
            for (int rep = 0; rep < 4; rep++) {
                int i = rep * 1024 + t;
                int ixj = i ^ jj;
                if (ixj > i) {
                    u64 a = lk[i], b = lk[ixj];
                    bool sw = ((i & kk) == 0) ? (a < b) : (a > b);
                    if (sw) { lk[i] = b; lk[ixj] = a; }
                }
            }
        }
    }
    __syncthreads();
#pragma unroll
    for (int rep = 0; rep < 2; rep++) {
        int i = rep * 1024 + t;
        bool suppb = true;
        float c0 = 0.f, c1 = 0.f, c2 = 0.f, c3 = 0.f, cs = 0.f;
        if (i < NKEEP) {
            u64 key = lk[i];
            u32 idx = ~(u32)(key & 0xFFFFFFFFull);
            cs = __uint_as_float((u32)(key >> 32));
            c0 = boxes[(size_t)idx * 4 + 0];
            c1 = boxes[(size_t)idx * 4 + 1];
            c2 = boxes[(size_t)idx * 4 + 2];
            c3 = boxes[(size_t)idx * 4 + 3];
            bool valid = ((c2 - c0) >= 16.f) && ((c3 - c1) >= 16.f) && (cs >= 0.05f);
            suppb = !valid;
        }
        cand5[i * 5 + 0] = c0;
        cand5[i * 5 + 1] = c1;
        cand5[i * 5 + 2] = c2;
        cand5[i * 5 + 3] = c3;
        cand5[i * 5 + 4] = cs;
        u64 bal = __ballot(suppb ? 1 : 0);
        if ((t & 63) == 0) suppws[i >> 6] = bal;
    }
}

// IoU > 0.7 bitmask, 64x64 tiles
__global__ __launch_bounds__(64) void k_mask(const float* __restrict__ cand5, u64* __restrict__ mask) {
    __shared__ float cb[64][5];
    int t = threadIdx.x;
    int bi = blockIdx.y, bj = blockIdx.x;
    int j = bj * 64 + t;
    {
        float b0 = cand5[j * 5 + 0], b1v = cand5[j * 5 + 1], b2v = cand5[j * 5 + 2], b3v = cand5[j * 5 + 3];
        cb[t][0] = b0; cb[t][1] = b1v; cb[t][2] = b2v; cb[t][3] = b3v;
        cb[t][4] = (b2v - b0) * (b3v - b1v);
    }
    __syncthreads();
    int i = bi * 64 + t;
    float r0 = cand5[i * 5 + 0], r1 = cand5[i * 5 + 1], r2 = cand5[i * 5 + 2], r3 = cand5[i * 5 + 3];
    float ra = (r2 - r0) * (r3 - r1);
    u64 bits = 0ull;
#pragma unroll 4
    for (int c = 0; c < 64; c++) {
        float lx = fmaxf(r0, cb[c][0]);
        float ly = fmaxf(r1, cb[c][1]);
        float rx = fminf(r2, cb[c][2]);
        float ry = fminf(r3, cb[c][3]);
        float w = fmaxf(rx - lx, 0.f);
        float h = fmaxf(ry - ly, 0.f);
        float inter = w * h;
        float iou = inter / fmaxf(ra + cb[c][4] - inter, 1e-6f);
        if (iou > 0.7f) bits |= (1ull << c);
    }
    mask[(size_t)i * 32 + bj] = bits;
}

// single-wave greedy NMS scan with depth-8 prefetch; writes first <=300 kept rows
__global__ __launch_bounds__(64) void k_scan(const u64* __restrict__ mask, const float* __restrict__ cand5,
                                             const u64* __restrict__ suppws, float* __restrict__ out) {
    int lane = threadIdx.x;
    u64 supp = (lane < 32) ? suppws[lane] : 0ull;
    u64 bufA[8], bufB[8];
    float dA[8], dB[8];
#pragma unroll
    for (int k = 0; k < 8; k++) {
        bufA[k] = (lane < 32) ? mask[(size_t)k * 32 + lane] : 0ull;
        dA[k] = (lane < 5) ? cand5[k * 5 + lane] : 0.f;
    }
    int kcount = 0;
    for (int gq = 0; gq < 256; gq++) {
        int base = gq * 8;
        if (gq < 255) {
            int nb = base + 8;
#pragma unroll
            for (int k = 0; k < 8; k++) {
                bufB[k] = (lane < 32) ? mask[(size_t)(nb + k) * 32 + lane] : 0ull;
                dB[k] = (lane < 5) ? cand5[(nb + k) * 5 + lane] : 0.f;
            }
        }
        int w = gq >> 3;
        u64 cur = __shfl(supp, w);
#pragma unroll
        for (int k = 0; k < 8; k++) {
            int i = base + k;
            if (i < NKEEP && !((cur >> (i & 63)) & 1ull)) {
                if (kcount < NTOPK) {
                    if (lane < 5) out[kcount * 5 + lane] = dA[k];
                    kcount++;
                }
                supp |= bufA[k];
                cur |= __shfl(bufA[k], w);
            }
        }
        if (kcount >= NTOPK) return;
#pragma unroll
        for (int k = 0; k < 8; k++) { bufA[k] = bufB[k]; dA[k] = dB[k]; }
    }
}

extern "C" void kernel_launch(void* const* d_in, const int* in_sizes, int n_in,
                              void* d_out, int out_size, void* d_ws, size_t ws_size,
                              hipStream_t stream) {
    (void)in_sizes; (void)n_in; (void)out_size;
    const float* fx = (const float*)d_in[0];
    const float* w1 = (const float*)d_in[1];
    const float* b1 = (const float*)d_in[2];
    const float* w2 = (const float*)d_in[3];
    const float* b2 = (const float*)d_in[4];
    const float* w3 = (const float*)d_in[5];
    const float* b3 = (const float*)d_in[6];
    const int* imh = (const int*)d_in[7];
    const int* imw = (const int*)d_in[8];

    char* ws = (char*)d_ws;
    float*  pacc   = (float*)(ws + OFF_PACC);
    double* pox    = (double*)(ws + OFF_POX);
    float*  boxes  = (float*)(ws + OFF_BOXES);
    float*  scores = (float*)(ws + OFF_SCORES);
    u32*    hist   = (u32*)(ws + OFF_HIST);
    u64*    keys   = (u64*)(ws + OFF_KEYS);
    float*  cand5  = (float*)(ws + OFF_CAND5);
    u64*    mask   = (u64*)(ws + OFF_MASK);
    u32*    misc   = (u32*)(ws + OFF_MISC);
    u64*    suppws = (u64*)(ws + OFF_MISC + 64);
    uint4*  preW   = (uint4*)(ws + OFF_PREW);
    float*  out    = (float*)d_out;

    k_init<<<256, 256, 0, stream>>>(hist, keys, misc, out);
    if (ws_size >= WS_NEED) {
        k_splitw<<<2304, 256, 0, stream>>>(w1, preW);
        k_conv1m<<<512, 512, 0, stream>>>(fx, preW, pacc);
    } else {
        k_conv1m_fb<<<512, 512, 0, stream>>>(fx, w1, pacc);
    }
    k_comb<<<8192, 256, 0, stream>>>(pacc, pacc + 2097152, b1);
    k_conv23<<<dim3(64, 4), 256, 0, stream>>>(pacc, w2, w3, pox);
    k_boxes<<<192, 256, 0, stream>>>(pox, b2, b3, imh, imw, boxes, scores, hist);
    k_scanhist<<<1, 256, 0, stream>>>(hist, misc);
    k_compact<<<192, 256, 0, stream>>>(scores, misc, keys);
    k_sort<<<1, 1024, 0, stream>>>(keys, boxes, cand5, suppws);
    k_mask<<<dim3(32, 32), 64, 0, stream>>>(cand5, mask);
    k_scan<<<1, 64, 0, stream>>>(mask, cand5, suppws, out);
}